// Round 1
// baseline (1241.681 us; speedup 1.0000x reference)
//
#include <hip/hip_runtime.h>
#include <float.h>

#define NB 1024
#define NT 200
#define ND 64
#define NH0 80
#define NH1 40
#define NROWS (NB*NT)

// stats layout in ws (floats): [0:80)=sum0 [80:160)=sumsq0 [160:200)=sum1 [200:240)=sumsq1
// ints at float idx 240,241: mask-format flags

// ---------------- mask dtype detection ----------------
__global__ void detect_mask_kernel(const unsigned* __restrict__ m, int* __restrict__ flags) {
  int i = blockIdx.x * 256 + threadIdx.x;
  if (i < NROWS / 4) {   // safe under byte(204800B)/int(819200B)/float interpretations
    unsigned v = m[i];
    if (v > 1u) atomicOr(&flags[0], 1);
    if (v != 0u && v != 1u && v != 0x3F800000u) atomicOr(&flags[1], 1);
  }
}

// ---------------- k1: h0 = x@W0 + b0, stats0 ----------------
template<bool STORE>
__global__ __launch_bounds__(256) void k1_kernel(
    const float* __restrict__ query, const float* __restrict__ key,
    const float* __restrict__ W0, const float* __restrict__ b0,
    float* __restrict__ h0, float* __restrict__ stats)
{
  __shared__ float sWb[64*80];   // W0b - W0c
  __shared__ float sWd[64*80];   // W0d
  __shared__ float sk[64*66];    // key tile, padded stride 66
  __shared__ float sq[64];
  __shared__ float sqc[80];      // b0 + q@(W0a+W0c)
  __shared__ float sred[160];
  int b = blockIdx.x, tid = threadIdx.x;

  for (int idx = tid; idx < 64*80; idx += 256) {
    int d = idx / 80, c = idx - d*80;
    sWb[idx] = W0[(64+d)*80 + c] - W0[(128+d)*80 + c];
    sWd[idx] = W0[(192+d)*80 + c];
  }
  if (tid < 64) sq[tid] = query[b*64 + tid];
  for (int i = tid; i < 160; i += 256) sred[i] = 0.f;
  __syncthreads();
  if (tid < 80) {
    float s = b0[tid];
    for (int d = 0; d < 64; ++d)
      s += sq[d] * (W0[d*80 + tid] + W0[(128+d)*80 + tid]);
    sqc[tid] = s;
  }
  int cg = tid & 15, rg = tid >> 4;          // 16 ch-groups x 5ch, 16 row-groups x 4 rows
  float accS[5] = {0,0,0,0,0}, accQ[5] = {0,0,0,0,0};
  const float* keyb = key + (size_t)b*NT*ND;

  for (int it = 0; it < 4; ++it) {
    int t0 = it * 64;
    __syncthreads();                          // protect prev tile reads (also orders sqc)
    for (int idx = tid; idx < 64*64; idx += 256) {
      int r = idx >> 6, d = idx & 63;
      int t = t0 + r;
      sk[r*66 + d] = (t < NT) ? keyb[t*ND + d] : 0.f;
    }
    __syncthreads();
    float acc[4][5];
#pragma unroll
    for (int j = 0; j < 4; ++j)
#pragma unroll
      for (int i = 0; i < 5; ++i) acc[j][i] = sqc[cg*5 + i];
    for (int d = 0; d < 64; ++d) {
      float sqd = sq[d];
      float kb[4], wb[5], wd[5];
#pragma unroll
      for (int j = 0; j < 4; ++j) kb[j] = sk[(rg*4 + j)*66 + d];
#pragma unroll
      for (int i = 0; i < 5; ++i) { wb[i] = sWb[d*80 + cg*5 + i]; wd[i] = sWd[d*80 + cg*5 + i]; }
#pragma unroll
      for (int j = 0; j < 4; ++j) {
        float qk = sqd * kb[j];
#pragma unroll
        for (int i = 0; i < 5; ++i)
          acc[j][i] = fmaf(kb[j], wb[i], fmaf(qk, wd[i], acc[j][i]));
      }
    }
#pragma unroll
    for (int j = 0; j < 4; ++j) {
      int t = t0 + rg*4 + j;
      if (t < NT) {
#pragma unroll
        for (int i = 0; i < 5; ++i) {
          float h = acc[j][i];
          if (STORE) h0[((size_t)b*NT + t)*NH0 + cg*5 + i] = h;
          accS[i] += h; accQ[i] += h*h;
        }
      }
    }
  }
#pragma unroll
  for (int i = 0; i < 5; ++i) {
    atomicAdd(&sred[cg*5 + i], accS[i]);
    atomicAdd(&sred[80 + cg*5 + i], accQ[i]);
  }
  __syncthreads();
  if (tid < 80) {
    atomicAdd(&stats[tid], sred[tid]);
    atomicAdd(&stats[80 + tid], sred[80 + tid]);
  }
}

// ---------------- k2 (load h0): h1 = dice0(h0)@W1 + b1, stats1 ----------------
__global__ __launch_bounds__(256) void k2_kernel(
    const float* __restrict__ h0, const float* __restrict__ W1,
    const float* __restrict__ b1, const float* __restrict__ alpha0,
    float* __restrict__ h1, float* __restrict__ stats)
{
  __shared__ float sW1[80*40];
  __shared__ float sb1[40];
  __shared__ float sm0[80], si0[80], sa0[80];
  int tid = threadIdx.x;
  for (int idx = tid; idx < 3200; idx += 256) sW1[idx] = W1[idx];
  if (tid < 40) sb1[tid] = b1[tid];
  if (tid < 80) {
    float invN = 1.f / (float)NROWS;
    float mean = stats[tid] * invN;
    float var  = stats[80 + tid] * invN - mean*mean;
    sm0[tid] = mean; si0[tid] = rsqrtf(var + 1e-9f); sa0[tid] = alpha0[tid];
  }
  __syncthreads();
  size_t r = (size_t)blockIdx.x * 256 + tid;      // grid 800 * 256 == 204800 exactly
  const float4* xr = (const float4*)(h0 + r*NH0);
  float acc[40];
#pragma unroll
  for (int c = 0; c < 40; ++c) acc[c] = sb1[c];
#pragma unroll 4
  for (int dq = 0; dq < 20; ++dq) {
    float4 xv = xr[dq];
#pragma unroll
    for (int u = 0; u < 4; ++u) {
      int d = dq*4 + u;
      float x = (&xv.x)[u];
      float xn = (x - sm0[d]) * si0[d];
      float p = 1.f / (1.f + __expf(-xn));
      float y = x * (sa0[d] + p*(1.f - sa0[d]));
      const float4* wr = (const float4*)(sW1 + d*40);
#pragma unroll
      for (int cq = 0; cq < 10; ++cq) {
        float4 w = wr[cq];
        acc[cq*4+0] = fmaf(y, w.x, acc[cq*4+0]);
        acc[cq*4+1] = fmaf(y, w.y, acc[cq*4+1]);
        acc[cq*4+2] = fmaf(y, w.z, acc[cq*4+2]);
        acc[cq*4+3] = fmaf(y, w.w, acc[cq*4+3]);
      }
    }
  }
  float4* orow = (float4*)(h1 + r*NH1);
#pragma unroll
  for (int cq = 0; cq < 10; ++cq) {
    float4 o; o.x = acc[cq*4+0]; o.y = acc[cq*4+1]; o.z = acc[cq*4+2]; o.w = acc[cq*4+3];
    orow[cq] = o;
  }
  int lane = tid & 63;
#pragma unroll
  for (int c = 0; c < 40; ++c) {
    float s = acc[c], q = acc[c]*acc[c];
#pragma unroll
    for (int off = 32; off > 0; off >>= 1) { s += __shfl_xor(s, off); q += __shfl_xor(q, off); }
    if (lane == 0) { atomicAdd(&stats[160 + c], s); atomicAdd(&stats[200 + c], q); }
  }
}

// ---------------- k2 fallback (recompute h0) ----------------
template<bool STOREH1>
__global__ __launch_bounds__(256) void k2_rec_kernel(
    const float* __restrict__ query, const float* __restrict__ key,
    const float* __restrict__ W0, const float* __restrict__ b0,
    const float* __restrict__ W1, const float* __restrict__ b1,
    const float* __restrict__ alpha0,
    float* __restrict__ h1, float* __restrict__ stats)
{
  __shared__ float sWb[64*80], sWd[64*80], sW1[80*40];
  __shared__ float sq[64], sqc[80], sb1[40];
  __shared__ float sm0[80], si0[80], sa0[80];
  int b = blockIdx.x, tid = threadIdx.x;
  for (int idx = tid; idx < 64*80; idx += 256) {
    int d = idx / 80, c = idx - d*80;
    sWb[idx] = W0[(64+d)*80 + c] - W0[(128+d)*80 + c];
    sWd[idx] = W0[(192+d)*80 + c];
  }
  for (int idx = tid; idx < 3200; idx += 256) sW1[idx] = W1[idx];
  if (tid < 64) sq[tid] = query[b*64 + tid];
  if (tid < 40) sb1[tid] = b1[tid];
  if (tid >= 64 && tid < 144) {
    int c = tid - 64;
    float invN = 1.f / (float)NROWS;
    float mean = stats[c] * invN;
    float var  = stats[80 + c] * invN - mean*mean;
    sm0[c] = mean; si0[c] = rsqrtf(var + 1e-9f); sa0[c] = alpha0[c];
  }
  __syncthreads();
  if (tid < 80) {
    float s = b0[tid];
    for (int d = 0; d < 64; ++d)
      s += sq[d] * (W0[d*80 + tid] + W0[(128+d)*80 + tid]);
    sqc[tid] = s;
  }
  __syncthreads();
  int t = tid;
  bool active = t < NT;
  float h0r[80];
#pragma unroll
  for (int c = 0; c < 80; ++c) h0r[c] = sqc[c];
  const float* krow = key + ((size_t)b*NT + (active ? t : 0))*ND;
  for (int dq = 0; dq < 16; ++dq) {
    float4 kv = ((const float4*)krow)[dq];
#pragma unroll
    for (int u = 0; u < 4; ++u) {
      int d = dq*4 + u;
      float kd = (&kv.x)[u];
      float qk = sq[d] * kd;
#pragma unroll
      for (int c = 0; c < 80; ++c)
        h0r[c] = fmaf(kd, sWb[d*80 + c], fmaf(qk, sWd[d*80 + c], h0r[c]));
    }
  }
  float h1r[40];
#pragma unroll
  for (int c = 0; c < 40; ++c) h1r[c] = sb1[c];
#pragma unroll
  for (int d = 0; d < 80; ++d) {
    float x = h0r[d];
    float xn = (x - sm0[d]) * si0[d];
    float p = 1.f / (1.f + __expf(-xn));
    float y = x * (sa0[d] + p*(1.f - sa0[d]));
#pragma unroll
    for (int c = 0; c < 40; ++c) h1r[c] = fmaf(y, sW1[d*40 + c], h1r[c]);
  }
  if (STOREH1 && active) {
    float4* orow = (float4*)(h1 + ((size_t)b*NT + t)*NH1);
#pragma unroll
    for (int cq = 0; cq < 10; ++cq) {
      float4 o; o.x = h1r[cq*4+0]; o.y = h1r[cq*4+1]; o.z = h1r[cq*4+2]; o.w = h1r[cq*4+3];
      orow[cq] = o;
    }
  }
  int lane = tid & 63;
#pragma unroll
  for (int c = 0; c < 40; ++c) {
    float v = active ? h1r[c] : 0.f;
    float s = v, q = v*v;
#pragma unroll
    for (int off = 32; off > 0; off >>= 1) { s += __shfl_xor(s, off); q += __shfl_xor(q, off); }
    if (lane == 0) { atomicAdd(&stats[160 + c], s); atomicAdd(&stats[200 + c], q); }
  }
}

// ---------------- k3 (load h1): dice1, scores, softmax, attn@key ----------------
__device__ __forceinline__ void softmax_and_out(
    int b, int tid, float sc, float* sp, float* sredm, float* ssum, float* sout,
    const float* __restrict__ key, float* __restrict__ out)
{
  sp[tid] = sc;
  float m = sc;
#pragma unroll
  for (int off = 32; off > 0; off >>= 1) m = fmaxf(m, __shfl_xor(m, off));
  if ((tid & 63) == 0) sredm[tid >> 6] = m;
  __syncthreads();
  float mm = fmaxf(fmaxf(sredm[0], sredm[1]), fmaxf(sredm[2], sredm[3]));
  float e = (sc > -FLT_MAX) ? __expf(sc - mm) : 0.f;
  float sv = e;
#pragma unroll
  for (int off = 32; off > 0; off >>= 1) sv += __shfl_xor(sv, off);
  if ((tid & 63) == 0) ssum[tid >> 6] = sv;
  __syncthreads();
  float inv = 1.f / (ssum[0] + ssum[1] + ssum[2] + ssum[3]);
  sp[tid] = e * inv;
  __syncthreads();
  int wid = tid >> 6, lane = tid & 63;
  const float* keyb = key + (size_t)b*NT*ND;
  float acc = 0.f;
  for (int t = wid; t < NT; t += 4) acc = fmaf(sp[t], keyb[t*ND + lane], acc);
  sout[tid] = acc;
  __syncthreads();
  if (tid < 64) out[b*64 + tid] = sout[tid] + sout[64+tid] + sout[128+tid] + sout[192+tid];
}

__device__ __forceinline__ bool read_mask(const void* mask, int mode, size_t mi) {
  if (mode == 0) return ((const int*)mask)[mi] != 0;
  if (mode == 1) return ((const unsigned char*)mask)[mi] != 0;
  return ((const float*)mask)[mi] != 0.f;
}

__global__ __launch_bounds__(256) void k3_kernel(
    const float* __restrict__ h1, const float* __restrict__ Wout,
    const float* __restrict__ bout, const float* __restrict__ alpha1,
    const void* __restrict__ mask, const float* __restrict__ key,
    const float* __restrict__ stats, const int* __restrict__ flags,
    float* __restrict__ out)
{
  __shared__ float sWo[40], sm1[40], si1[40], sa1[40];
  __shared__ float sp[256], sredm[4], ssum[4], sout[256];
  int b = blockIdx.x, tid = threadIdx.x;
  if (tid < 40) {
    sWo[tid] = Wout[tid];
    float invN = 1.f / (float)NROWS;
    float mean = stats[160 + tid] * invN;
    float var  = stats[200 + tid] * invN - mean*mean;
    sm1[tid] = mean; si1[tid] = rsqrtf(var + 1e-9f); sa1[tid] = alpha1[tid];
  }
  __syncthreads();
  int mode = (flags[0] == 0) ? 0 : ((flags[1] == 0) ? 2 : 1);
  float sc = -FLT_MAX;
  if (tid < NT) {
    const float4* xr = (const float4*)(h1 + ((size_t)b*NT + tid)*NH1);
    float s = bout[0];
#pragma unroll
    for (int cq = 0; cq < 10; ++cq) {
      float4 xv = xr[cq];
#pragma unroll
      for (int u = 0; u < 4; ++u) {
        int c = cq*4 + u;
        float x = (&xv.x)[u];
        float xn = (x - sm1[c]) * si1[c];
        float p = 1.f / (1.f + __expf(-xn));
        float y = x * (sa1[c] + p*(1.f - sa1[c]));
        s = fmaf(y, sWo[c], s);
      }
    }
    if (read_mask(mask, mode, (size_t)b*NT + tid)) sc = s;
  }
  softmax_and_out(b, tid, sc, sp, sredm, ssum, sout, key, out);
}

// ---------------- k3 fallback (full recompute) ----------------
__global__ __launch_bounds__(256) void k3_rec_kernel(
    const float* __restrict__ query, const float* __restrict__ key,
    const float* __restrict__ W0, const float* __restrict__ b0,
    const float* __restrict__ W1, const float* __restrict__ b1,
    const float* __restrict__ alpha0, const float* __restrict__ Wout,
    const float* __restrict__ bout, const float* __restrict__ alpha1,
    const void* __restrict__ mask,
    const float* __restrict__ stats, const int* __restrict__ flags,
    float* __restrict__ out)
{
  __shared__ float sWb[64*80], sWd[64*80], sW1[80*40];
  __shared__ float sq[64], sqc[80], sb1[40];
  __shared__ float sm0[80], si0[80], sa0[80];
  __shared__ float sWo[40], sm1[40], si1[40], sa1[40];
  __shared__ float sp[256], sredm[4], ssum[4], sout[256];
  int b = blockIdx.x, tid = threadIdx.x;
  for (int idx = tid; idx < 64*80; idx += 256) {
    int d = idx / 80, c = idx - d*80;
    sWb[idx] = W0[(64+d)*80 + c] - W0[(128+d)*80 + c];
    sWd[idx] = W0[(192+d)*80 + c];
  }
  for (int idx = tid; idx < 3200; idx += 256) sW1[idx] = W1[idx];
  if (tid < 64) sq[tid] = query[b*64 + tid];
  if (tid < 40) sb1[tid] = b1[tid];
  if (tid >= 64 && tid < 144) {
    int c = tid - 64;
    float invN = 1.f / (float)NROWS;
    float mean = stats[c] * invN;
    float var  = stats[80 + c] * invN - mean*mean;
    sm0[c] = mean; si0[c] = rsqrtf(var + 1e-9f); sa0[c] = alpha0[c];
  }
  if (tid >= 144 && tid < 184) {
    int c = tid - 144;
    float invN = 1.f / (float)NROWS;
    float mean = stats[160 + c] * invN;
    float var  = stats[200 + c] * invN - mean*mean;
    sm1[c] = mean; si1[c] = rsqrtf(var + 1e-9f); sa1[c] = alpha1[c];
    sWo[c] = Wout[c];
  }
  __syncthreads();
  if (tid < 80) {
    float s = b0[tid];
    for (int d = 0; d < 64; ++d)
      s += sq[d] * (W0[d*80 + tid] + W0[(128+d)*80 + tid]);
    sqc[tid] = s;
  }
  __syncthreads();
  int t = tid;
  bool active = t < NT;
  int mode = (flags[0] == 0) ? 0 : ((flags[1] == 0) ? 2 : 1);
  float sc = -FLT_MAX;
  {
    float h0r[80];
#pragma unroll
    for (int c = 0; c < 80; ++c) h0r[c] = sqc[c];
    const float* krow = key + ((size_t)b*NT + (active ? t : 0))*ND;
    for (int dq = 0; dq < 16; ++dq) {
      float4 kv = ((const float4*)krow)[dq];
#pragma unroll
      for (int u = 0; u < 4; ++u) {
        int d = dq*4 + u;
        float kd = (&kv.x)[u];
        float qk = sq[d] * kd;
#pragma unroll
        for (int c = 0; c < 80; ++c)
          h0r[c] = fmaf(kd, sWb[d*80 + c], fmaf(qk, sWd[d*80 + c], h0r[c]));
      }
    }
    float h1r[40];
#pragma unroll
    for (int c = 0; c < 40; ++c) h1r[c] = sb1[c];
#pragma unroll
    for (int d = 0; d < 80; ++d) {
      float x = h0r[d];
      float xn = (x - sm0[d]) * si0[d];
      float p = 1.f / (1.f + __expf(-xn));
      float y = x * (sa0[d] + p*(1.f - sa0[d]));
#pragma unroll
      for (int c = 0; c < 40; ++c) h1r[c] = fmaf(y, sW1[d*40 + c], h1r[c]);
    }
    float s = bout[0];
#pragma unroll
    for (int c = 0; c < 40; ++c) {
      float x = h1r[c];
      float xn = (x - sm1[c]) * si1[c];
      float p = 1.f / (1.f + __expf(-xn));
      float y = x * (sa1[c] + p*(1.f - sa1[c]));
      s = fmaf(y, sWo[c], s);
    }
    if (active && read_mask(mask, mode, (size_t)b*NT + t)) sc = s;
  }
  softmax_and_out(b, tid, sc, sp, sredm, ssum, sout, key, out);
}

extern "C" void kernel_launch(void* const* d_in, const int* in_sizes, int n_in,
                              void* d_out, int out_size, void* d_ws, size_t ws_size,
                              hipStream_t stream) {
  const float* query  = (const float*)d_in[0];
  const float* key    = (const float*)d_in[1];
  const void*  mask   = d_in[2];
  const float* W0     = (const float*)d_in[3];
  const float* b0     = (const float*)d_in[4];
  const float* alpha0 = (const float*)d_in[5];
  const float* W1     = (const float*)d_in[6];
  const float* b1     = (const float*)d_in[7];
  const float* alpha1 = (const float*)d_in[8];
  const float* Wout   = (const float*)d_in[9];
  const float* bout   = (const float*)d_in[10];
  float* out = (float*)d_out;

  char* wsb = (char*)d_ws;
  float* stats = (float*)wsb;
  int* flags = (int*)(wsb + 240*4);
  const size_t h0B = (size_t)NROWS * NH0 * 4;
  const size_t h1B = (size_t)NROWS * NH1 * 4;
  bool storeH0 = ws_size >= 1024 + h0B + h1B;
  bool storeH1 = storeH0 || (ws_size >= 1024 + h1B);
  float* h0 = (float*)(wsb + 1024);
  float* h1 = storeH0 ? (float*)(wsb + 1024 + h0B) : (float*)(wsb + 1024);

  hipMemsetAsync(d_ws, 0, 1024, stream);
  detect_mask_kernel<<<200, 256, 0, stream>>>((const unsigned*)mask, flags);

  if (storeH0) {
    k1_kernel<true><<<NB, 256, 0, stream>>>(query, key, W0, b0, h0, stats);
    k2_kernel<<<NROWS/256, 256, 0, stream>>>(h0, W1, b1, alpha0, h1, stats);
    k3_kernel<<<NB, 256, 0, stream>>>(h1, Wout, bout, alpha1, mask, key, stats, flags, out);
  } else if (storeH1) {
    k1_kernel<false><<<NB, 256, 0, stream>>>(query, key, W0, b0, nullptr, stats);
    k2_rec_kernel<true><<<NB, 256, 0, stream>>>(query, key, W0, b0, W1, b1, alpha0, h1, stats);
    k3_kernel<<<NB, 256, 0, stream>>>(h1, Wout, bout, alpha1, mask, key, stats, flags, out);
  } else {
    k1_kernel<false><<<NB, 256, 0, stream>>>(query, key, W0, b0, nullptr, stats);
    k2_rec_kernel<false><<<NB, 256, 0, stream>>>(query, key, W0, b0, W1, b1, alpha0, nullptr, stats);
    k3_rec_kernel<<<NB, 256, 0, stream>>>(query, key, W0, b0, W1, b1, alpha0, Wout, bout, alpha1,
                                          mask, stats, flags, out);
  }
}

// Round 2
// 234.455 us; speedup vs baseline: 5.2960x; 5.2960x over previous
//
#include <hip/hip_runtime.h>
#include <float.h>

#define NB 1024
#define NT 200
#define ND 64
#define NH0 80
#define NH1 40
#define NROWS (NB*NT)
#define P0_STRIDE 1024
#define P1_STRIDE 1024

// ws layout (bytes):
//   [0, 960):  stats floats: mean0[0:80) inv0[80:160) mean1[160:200) inv1[200:240)
//              flags ints at float idx 240, 241
//   [1024, +640K):   p0 [160][P0_STRIDE]  per-block partials (sum ch<80, sumsq ch 80..159)
//   [656384, +320K): p1 [80][P1_STRIDE]   per-block partials (sum ch<40, sumsq ch 40..79)
//   [984064, ...):   h0 [NROWS][80], then h1 [NROWS][40]

// ---------------- mask dtype detection ----------------
__global__ void detect_mask_kernel(const unsigned* __restrict__ m, int* __restrict__ flags) {
  int i = blockIdx.x * 256 + threadIdx.x;
  if (i < NROWS / 4) {   // safe under byte(204800B)/int(819200B)/float interpretations
    unsigned v = m[i];
    if (v > 1u) atomicOr(&flags[0], 1);
    if (v != 0u && v != 1u && v != 0x3F800000u) atomicOr(&flags[1], 1);
  }
}

// ---------------- partial -> mean/inv reduction ----------------
__global__ __launch_bounds__(256) void reduce_stats_kernel(
    const float* __restrict__ p, int stride, int nblk, int nch,
    float* __restrict__ mean_out, float* __restrict__ inv_out)
{
  int c = blockIdx.x, tid = threadIdx.x;
  float s = 0.f, q = 0.f;
  for (int j = tid; j < nblk; j += 256) {
    s += p[(size_t)c*stride + j];
    q += p[(size_t)(nch + c)*stride + j];
  }
#pragma unroll
  for (int off = 32; off > 0; off >>= 1) { s += __shfl_xor(s, off); q += __shfl_xor(q, off); }
  __shared__ float ss[4], sq[4];
  if ((tid & 63) == 0) { ss[tid >> 6] = s; sq[tid >> 6] = q; }
  __syncthreads();
  if (tid == 0) {
    float S = ss[0]+ss[1]+ss[2]+ss[3], Q = sq[0]+sq[1]+sq[2]+sq[3];
    float invN = 1.f / (float)NROWS;
    float mean = S * invN;
    float var  = Q * invN - mean*mean;
    mean_out[c] = mean;
    inv_out[c]  = rsqrtf(var + 1e-9f);
  }
}

// ---------------- k1: h0 = x@W0 + b0, per-block stats0 partials ----------------
template<bool STORE>
__global__ __launch_bounds__(256) void k1_kernel(
    const float* __restrict__ query, const float* __restrict__ key,
    const float* __restrict__ W0, const float* __restrict__ b0,
    float* __restrict__ h0, float* __restrict__ p0)
{
  __shared__ float sWb[64*80];   // W0b - W0c
  __shared__ float sWd[64*80];   // W0d
  __shared__ float sk[64*66];    // key tile, padded stride 66
  __shared__ float sq[64];
  __shared__ float sqc[80];      // b0 + q@(W0a+W0c)
  __shared__ float sred[160];
  int b = blockIdx.x, tid = threadIdx.x;

  for (int idx = tid; idx < 64*80; idx += 256) {
    int d = idx / 80, c = idx - d*80;
    sWb[idx] = W0[(64+d)*80 + c] - W0[(128+d)*80 + c];
    sWd[idx] = W0[(192+d)*80 + c];
  }
  if (tid < 64) sq[tid] = query[b*64 + tid];
  for (int i = tid; i < 160; i += 256) sred[i] = 0.f;
  __syncthreads();
  if (tid < 80) {
    float s = b0[tid];
    for (int d = 0; d < 64; ++d)
      s += sq[d] * (W0[d*80 + tid] + W0[(128+d)*80 + tid]);
    sqc[tid] = s;
  }
  int cg = tid & 15, rg = tid >> 4;          // 16 ch-groups x 5ch, 16 row-groups x 4 rows
  float accS[5] = {0,0,0,0,0}, accQ[5] = {0,0,0,0,0};
  const float* keyb = key + (size_t)b*NT*ND;

  for (int it = 0; it < 4; ++it) {
    int t0 = it * 64;
    __syncthreads();                          // protect prev tile reads (also orders sqc)
    for (int idx = tid; idx < 64*64; idx += 256) {
      int r = idx >> 6, d = idx & 63;
      int t = t0 + r;
      sk[r*66 + d] = (t < NT) ? keyb[t*ND + d] : 0.f;
    }
    __syncthreads();
    float acc[4][5];
#pragma unroll
    for (int j = 0; j < 4; ++j)
#pragma unroll
      for (int i = 0; i < 5; ++i) acc[j][i] = sqc[cg*5 + i];
    for (int d = 0; d < 64; ++d) {
      float sqd = sq[d];
      float kb[4], wb[5], wd[5];
#pragma unroll
      for (int j = 0; j < 4; ++j) kb[j] = sk[(rg*4 + j)*66 + d];
#pragma unroll
      for (int i = 0; i < 5; ++i) { wb[i] = sWb[d*80 + cg*5 + i]; wd[i] = sWd[d*80 + cg*5 + i]; }
#pragma unroll
      for (int j = 0; j < 4; ++j) {
        float qk = sqd * kb[j];
#pragma unroll
        for (int i = 0; i < 5; ++i)
          acc[j][i] = fmaf(kb[j], wb[i], fmaf(qk, wd[i], acc[j][i]));
      }
    }
#pragma unroll
    for (int j = 0; j < 4; ++j) {
      int t = t0 + rg*4 + j;
      if (t < NT) {
#pragma unroll
        for (int i = 0; i < 5; ++i) {
          float h = acc[j][i];
          if (STORE) h0[((size_t)b*NT + t)*NH0 + cg*5 + i] = h;
          accS[i] += h; accQ[i] += h*h;
        }
      }
    }
  }
#pragma unroll
  for (int i = 0; i < 5; ++i) {
    atomicAdd(&sred[cg*5 + i], accS[i]);
    atomicAdd(&sred[80 + cg*5 + i], accQ[i]);
  }
  __syncthreads();
  if (tid < 160) p0[(size_t)tid * P0_STRIDE + b] = sred[tid];
}

// ---------------- k2 (load h0): h1 = dice0(h0)@W1 + b1, stats1 partials ----------------
__global__ __launch_bounds__(256) void k2_kernel(
    const float* __restrict__ h0, const float* __restrict__ W1,
    const float* __restrict__ b1, const float* __restrict__ alpha0,
    float* __restrict__ h1, const float* __restrict__ stats,
    float* __restrict__ p1)
{
  __shared__ float sW1[80*40];
  __shared__ float sb1[40];
  __shared__ float sm0[80], si0[80], sa0[80];
  __shared__ float swp[4*80];
  int tid = threadIdx.x;
  for (int idx = tid; idx < 3200; idx += 256) sW1[idx] = W1[idx];
  if (tid < 40) sb1[tid] = b1[tid];
  if (tid < 80) {
    sm0[tid] = stats[tid]; si0[tid] = stats[80 + tid]; sa0[tid] = alpha0[tid];
  }
  __syncthreads();
  size_t r = (size_t)blockIdx.x * 256 + tid;      // grid 800 * 256 == 204800 exactly
  const float4* xr = (const float4*)(h0 + r*NH0);
  float acc[40];
#pragma unroll
  for (int c = 0; c < 40; ++c) acc[c] = sb1[c];
#pragma unroll 4
  for (int dq = 0; dq < 20; ++dq) {
    float4 xv = xr[dq];
#pragma unroll
    for (int u = 0; u < 4; ++u) {
      int d = dq*4 + u;
      float x = (&xv.x)[u];
      float xn = (x - sm0[d]) * si0[d];
      float p = 1.f / (1.f + __expf(-xn));
      float y = x * (sa0[d] + p*(1.f - sa0[d]));
      const float4* wr = (const float4*)(sW1 + d*40);
#pragma unroll
      for (int cq = 0; cq < 10; ++cq) {
        float4 w = wr[cq];
        acc[cq*4+0] = fmaf(y, w.x, acc[cq*4+0]);
        acc[cq*4+1] = fmaf(y, w.y, acc[cq*4+1]);
        acc[cq*4+2] = fmaf(y, w.z, acc[cq*4+2]);
        acc[cq*4+3] = fmaf(y, w.w, acc[cq*4+3]);
      }
    }
  }
  float4* orow = (float4*)(h1 + r*NH1);
#pragma unroll
  for (int cq = 0; cq < 10; ++cq) {
    float4 o; o.x = acc[cq*4+0]; o.y = acc[cq*4+1]; o.z = acc[cq*4+2]; o.w = acc[cq*4+3];
    orow[cq] = o;
  }
  int lane = tid & 63, wid = tid >> 6;
#pragma unroll
  for (int c = 0; c < 40; ++c) {
    float s = acc[c], q = acc[c]*acc[c];
#pragma unroll
    for (int off = 32; off > 0; off >>= 1) { s += __shfl_xor(s, off); q += __shfl_xor(q, off); }
    if (lane == 0) { swp[wid*80 + c] = s; swp[wid*80 + 40 + c] = q; }
  }
  __syncthreads();
  if (tid < 80) {
    float v = swp[tid] + swp[80+tid] + swp[160+tid] + swp[240+tid];
    p1[(size_t)tid * P1_STRIDE + blockIdx.x] = v;
  }
}

// ---------------- k2 fallback (recompute h0) ----------------
template<bool STOREH1>
__global__ __launch_bounds__(256) void k2_rec_kernel(
    const float* __restrict__ query, const float* __restrict__ key,
    const float* __restrict__ W0, const float* __restrict__ b0,
    const float* __restrict__ W1, const float* __restrict__ b1,
    const float* __restrict__ alpha0,
    float* __restrict__ h1, const float* __restrict__ stats,
    float* __restrict__ p1)
{
  __shared__ float sWb[64*80], sWd[64*80], sW1[80*40];
  __shared__ float sq[64], sqc[80], sb1[40];
  __shared__ float sm0[80], si0[80], sa0[80];
  __shared__ float swp[4*80];
  int b = blockIdx.x, tid = threadIdx.x;
  for (int idx = tid; idx < 64*80; idx += 256) {
    int d = idx / 80, c = idx - d*80;
    sWb[idx] = W0[(64+d)*80 + c] - W0[(128+d)*80 + c];
    sWd[idx] = W0[(192+d)*80 + c];
  }
  for (int idx = tid; idx < 3200; idx += 256) sW1[idx] = W1[idx];
  if (tid < 64) sq[tid] = query[b*64 + tid];
  if (tid < 40) sb1[tid] = b1[tid];
  if (tid >= 64 && tid < 144) {
    int c = tid - 64;
    sm0[c] = stats[c]; si0[c] = stats[80 + c]; sa0[c] = alpha0[c];
  }
  __syncthreads();
  if (tid < 80) {
    float s = b0[tid];
    for (int d = 0; d < 64; ++d)
      s += sq[d] * (W0[d*80 + tid] + W0[(128+d)*80 + tid]);
    sqc[tid] = s;
  }
  __syncthreads();
  int t = tid;
  bool active = t < NT;
  float h0r[80];
#pragma unroll
  for (int c = 0; c < 80; ++c) h0r[c] = sqc[c];
  const float* krow = key + ((size_t)b*NT + (active ? t : 0))*ND;
  for (int dq = 0; dq < 16; ++dq) {
    float4 kv = ((const float4*)krow)[dq];
#pragma unroll
    for (int u = 0; u < 4; ++u) {
      int d = dq*4 + u;
      float kd = (&kv.x)[u];
      float qk = sq[d] * kd;
#pragma unroll
      for (int c = 0; c < 80; ++c)
        h0r[c] = fmaf(kd, sWb[d*80 + c], fmaf(qk, sWd[d*80 + c], h0r[c]));
    }
  }
  float h1r[40];
#pragma unroll
  for (int c = 0; c < 40; ++c) h1r[c] = sb1[c];
#pragma unroll
  for (int d = 0; d < 80; ++d) {
    float x = h0r[d];
    float xn = (x - sm0[d]) * si0[d];
    float p = 1.f / (1.f + __expf(-xn));
    float y = x * (sa0[d] + p*(1.f - sa0[d]));
#pragma unroll
    for (int c = 0; c < 40; ++c) h1r[c] = fmaf(y, sW1[d*40 + c], h1r[c]);
  }
  if (STOREH1 && active) {
    float4* orow = (float4*)(h1 + ((size_t)b*NT + t)*NH1);
#pragma unroll
    for (int cq = 0; cq < 10; ++cq) {
      float4 o; o.x = h1r[cq*4+0]; o.y = h1r[cq*4+1]; o.z = h1r[cq*4+2]; o.w = h1r[cq*4+3];
      orow[cq] = o;
    }
  }
  int lane = tid & 63, wid = tid >> 6;
#pragma unroll
  for (int c = 0; c < 40; ++c) {
    float v = active ? h1r[c] : 0.f;
    float s = v, q = v*v;
#pragma unroll
    for (int off = 32; off > 0; off >>= 1) { s += __shfl_xor(s, off); q += __shfl_xor(q, off); }
    if (lane == 0) { swp[wid*80 + c] = s; swp[wid*80 + 40 + c] = q; }
  }
  __syncthreads();
  if (tid < 80) {
    float v = swp[tid] + swp[80+tid] + swp[160+tid] + swp[240+tid];
    p1[(size_t)tid * P1_STRIDE + b] = v;
  }
}

// ---------------- k3: dice1, scores, softmax, attn@key ----------------
__device__ __forceinline__ void softmax_and_out(
    int b, int tid, float sc, float* sp, float* sredm, float* ssum, float* sout,
    const float* __restrict__ key, float* __restrict__ out)
{
  float m = sc;
#pragma unroll
  for (int off = 32; off > 0; off >>= 1) m = fmaxf(m, __shfl_xor(m, off));
  if ((tid & 63) == 0) sredm[tid >> 6] = m;
  __syncthreads();
  float mm = fmaxf(fmaxf(sredm[0], sredm[1]), fmaxf(sredm[2], sredm[3]));
  float e = (sc > -FLT_MAX) ? __expf(sc - mm) : 0.f;
  float sv = e;
#pragma unroll
  for (int off = 32; off > 0; off >>= 1) sv += __shfl_xor(sv, off);
  if ((tid & 63) == 0) ssum[tid >> 6] = sv;
  __syncthreads();
  float inv = 1.f / (ssum[0] + ssum[1] + ssum[2] + ssum[3]);
  sp[tid] = e * inv;
  __syncthreads();
  int wid = tid >> 6, lane = tid & 63;
  const float* keyb = key + (size_t)b*NT*ND;
  float acc = 0.f;
  for (int t = wid; t < NT; t += 4) acc = fmaf(sp[t], keyb[t*ND + lane], acc);
  sout[tid] = acc;
  __syncthreads();
  if (tid < 64) out[b*64 + tid] = sout[tid] + sout[64+tid] + sout[128+tid] + sout[192+tid];
}

__device__ __forceinline__ bool read_mask(const void* mask, int mode, size_t mi) {
  if (mode == 0) return ((const int*)mask)[mi] != 0;
  if (mode == 1) return ((const unsigned char*)mask)[mi] != 0;
  return ((const float*)mask)[mi] != 0.f;
}

__global__ __launch_bounds__(256) void k3_kernel(
    const float* __restrict__ h1, const float* __restrict__ Wout,
    const float* __restrict__ bout, const float* __restrict__ alpha1,
    const void* __restrict__ mask, const float* __restrict__ key,
    const float* __restrict__ stats, const int* __restrict__ flags,
    float* __restrict__ out)
{
  __shared__ float sWo[40], sm1[40], si1[40], sa1[40];
  __shared__ float sp[256], sredm[4], ssum[4], sout[256];
  int b = blockIdx.x, tid = threadIdx.x;
  if (tid < 40) {
    sWo[tid] = Wout[tid];
    sm1[tid] = stats[160 + tid]; si1[tid] = stats[200 + tid]; sa1[tid] = alpha1[tid];
  }
  __syncthreads();
  int mode = (flags[0] == 0) ? 0 : ((flags[1] == 0) ? 2 : 1);
  float sc = -FLT_MAX;
  if (tid < NT) {
    const float4* xr = (const float4*)(h1 + ((size_t)b*NT + tid)*NH1);
    float s = bout[0];
#pragma unroll
    for (int cq = 0; cq < 10; ++cq) {
      float4 xv = xr[cq];
#pragma unroll
      for (int u = 0; u < 4; ++u) {
        int c = cq*4 + u;
        float x = (&xv.x)[u];
        float xn = (x - sm1[c]) * si1[c];
        float p = 1.f / (1.f + __expf(-xn));
        float y = x * (sa1[c] + p*(1.f - sa1[c]));
        s = fmaf(y, sWo[c], s);
      }
    }
    if (read_mask(mask, mode, (size_t)b*NT + tid)) sc = s;
  }
  softmax_and_out(b, tid, sc, sp, sredm, ssum, sout, key, out);
}

// ---------------- k3 fallback (full recompute) ----------------
__global__ __launch_bounds__(256) void k3_rec_kernel(
    const float* __restrict__ query, const float* __restrict__ key,
    const float* __restrict__ W0, const float* __restrict__ b0,
    const float* __restrict__ W1, const float* __restrict__ b1,
    const float* __restrict__ alpha0, const float* __restrict__ Wout,
    const float* __restrict__ bout, const float* __restrict__ alpha1,
    const void* __restrict__ mask,
    const float* __restrict__ stats, const int* __restrict__ flags,
    float* __restrict__ out)
{
  __shared__ float sWb[64*80], sWd[64*80], sW1[80*40];
  __shared__ float sq[64], sqc[80], sb1[40];
  __shared__ float sm0[80], si0[80], sa0[80];
  __shared__ float sWo[40], sm1[40], si1[40], sa1[40];
  __shared__ float sp[256], sredm[4], ssum[4], sout[256];
  int b = blockIdx.x, tid = threadIdx.x;
  for (int idx = tid; idx < 64*80; idx += 256) {
    int d = idx / 80, c = idx - d*80;
    sWb[idx] = W0[(64+d)*80 + c] - W0[(128+d)*80 + c];
    sWd[idx] = W0[(192+d)*80 + c];
  }
  for (int idx = tid; idx < 3200; idx += 256) sW1[idx] = W1[idx];
  if (tid < 64) sq[tid] = query[b*64 + tid];
  if (tid < 40) sb1[tid] = b1[tid];
  if (tid >= 64 && tid < 144) {
    int c = tid - 64;
    sm0[c] = stats[c]; si0[c] = stats[80 + c]; sa0[c] = alpha0[c];
  }
  if (tid >= 144 && tid < 184) {
    int c = tid - 144;
    sm1[c] = stats[160 + c]; si1[c] = stats[200 + c]; sa1[c] = alpha1[c];
    sWo[c] = Wout[c];
  }
  __syncthreads();
  if (tid < 80) {
    float s = b0[tid];
    for (int d = 0; d < 64; ++d)
      s += sq[d] * (W0[d*80 + tid] + W0[(128+d)*80 + tid]);
    sqc[tid] = s;
  }
  __syncthreads();
  int t = tid;
  bool active = t < NT;
  int mode = (flags[0] == 0) ? 0 : ((flags[1] == 0) ? 2 : 1);
  float sc = -FLT_MAX;
  {
    float h0r[80];
#pragma unroll
    for (int c = 0; c < 80; ++c) h0r[c] = sqc[c];
    const float* krow = key + ((size_t)b*NT + (active ? t : 0))*ND;
    for (int dq = 0; dq < 16; ++dq) {
      float4 kv = ((const float4*)krow)[dq];
#pragma unroll
      for (int u = 0; u < 4; ++u) {
        int d = dq*4 + u;
        float kd = (&kv.x)[u];
        float qk = sq[d] * kd;
#pragma unroll
        for (int c = 0; c < 80; ++c)
          h0r[c] = fmaf(kd, sWb[d*80 + c], fmaf(qk, sWd[d*80 + c], h0r[c]));
      }
    }
    float h1r[40];
#pragma unroll
    for (int c = 0; c < 40; ++c) h1r[c] = sb1[c];
#pragma unroll
    for (int d = 0; d < 80; ++d) {
      float x = h0r[d];
      float xn = (x - sm0[d]) * si0[d];
      float p = 1.f / (1.f + __expf(-xn));
      float y = x * (sa0[d] + p*(1.f - sa0[d]));
#pragma unroll
      for (int c = 0; c < 40; ++c) h1r[c] = fmaf(y, sW1[d*40 + c], h1r[c]);
    }
    float s = bout[0];
#pragma unroll
    for (int c = 0; c < 40; ++c) {
      float x = h1r[c];
      float xn = (x - sm1[c]) * si1[c];
      float p = 1.f / (1.f + __expf(-xn));
      float y = x * (sa1[c] + p*(1.f - sa1[c]));
      s = fmaf(y, sWo[c], s);
    }
    if (active && read_mask(mask, mode, (size_t)b*NT + t)) sc = s;
  }
  softmax_and_out(b, tid, sc, sp, sredm, ssum, sout, key, out);
}

extern "C" void kernel_launch(void* const* d_in, const int* in_sizes, int n_in,
                              void* d_out, int out_size, void* d_ws, size_t ws_size,
                              hipStream_t stream) {
  const float* query  = (const float*)d_in[0];
  const float* key    = (const float*)d_in[1];
  const void*  mask   = d_in[2];
  const float* W0     = (const float*)d_in[3];
  const float* b0     = (const float*)d_in[4];
  const float* alpha0 = (const float*)d_in[5];
  const float* W1     = (const float*)d_in[6];
  const float* b1     = (const float*)d_in[7];
  const float* alpha1 = (const float*)d_in[8];
  const float* Wout   = (const float*)d_in[9];
  const float* bout   = (const float*)d_in[10];
  float* out = (float*)d_out;

  char* wsb = (char*)d_ws;
  float* stats = (float*)wsb;
  int* flags = (int*)(wsb + 240*4);
  const size_t off_p0 = 1024;
  const size_t p0B = (size_t)160 * P0_STRIDE * 4;           // 640 KB
  const size_t off_p1 = off_p0 + p0B;
  const size_t p1B = (size_t)80 * P1_STRIDE * 4;            // 320 KB
  const size_t off_h0 = off_p1 + p1B;                       // 984064
  const size_t h0B = (size_t)NROWS * NH0 * 4;
  const size_t h1B = (size_t)NROWS * NH1 * 4;
  float* p0 = (float*)(wsb + off_p0);
  float* p1 = (float*)(wsb + off_p1);
  float* h0 = (float*)(wsb + off_h0);
  bool storeH0 = ws_size >= off_h0 + h0B + h1B;
  bool storeH1 = storeH0 || (ws_size >= off_h0 + h1B);
  float* h1 = storeH0 ? (float*)(wsb + off_h0 + h0B) : (float*)(wsb + off_h0);

  hipMemsetAsync(d_ws, 0, 1024, stream);
  detect_mask_kernel<<<200, 256, 0, stream>>>((const unsigned*)mask, flags);

  if (storeH0) {
    k1_kernel<true><<<NB, 256, 0, stream>>>(query, key, W0, b0, h0, p0);
    reduce_stats_kernel<<<80, 256, 0, stream>>>(p0, P0_STRIDE, NB, 80, stats, stats + 80);
    k2_kernel<<<NROWS/256, 256, 0, stream>>>(h0, W1, b1, alpha0, h1, stats, p1);
    reduce_stats_kernel<<<40, 256, 0, stream>>>(p1, P1_STRIDE, NROWS/256, 40, stats + 160, stats + 200);
    k3_kernel<<<NB, 256, 0, stream>>>(h1, Wout, bout, alpha1, mask, key, stats, flags, out);
  } else if (storeH1) {
    k1_kernel<false><<<NB, 256, 0, stream>>>(query, key, W0, b0, nullptr, p0);
    reduce_stats_kernel<<<80, 256, 0, stream>>>(p0, P0_STRIDE, NB, 80, stats, stats + 80);
    k2_rec_kernel<true><<<NB, 256, 0, stream>>>(query, key, W0, b0, W1, b1, alpha0, h1, stats, p1);
    reduce_stats_kernel<<<40, 256, 0, stream>>>(p1, P1_STRIDE, NB, 40, stats + 160, stats + 200);
    k3_kernel<<<NB, 256, 0, stream>>>(h1, Wout, bout, alpha1, mask, key, stats, flags, out);
  } else {
    k1_kernel<false><<<NB, 256, 0, stream>>>(query, key, W0, b0, nullptr, p0);
    reduce_stats_kernel<<<80, 256, 0, stream>>>(p0, P0_STRIDE, NB, 80, stats, stats + 80);
    k2_rec_kernel<false><<<NB, 256, 0, stream>>>(query, key, W0, b0, W1, b1, alpha0, nullptr, stats, p1);
    reduce_stats_kernel<<<40, 256, 0, stream>>>(p1, P1_STRIDE, NB, 40, stats + 160, stats + 200);
    k3_rec_kernel<<<NB, 256, 0, stream>>>(query, key, W0, b0, W1, b1, alpha0, Wout, bout, alpha1,
                                          mask, stats, flags, out);
  }
}

// Round 3
// 154.357 us; speedup vs baseline: 8.0442x; 1.5189x over previous
//
#include <hip/hip_runtime.h>
#include <float.h>

#define NB 1024
#define NT 200
#define ND 64
#define NH0 80
#define NH1 40
#define NROWS (NB*NT)
#define P0_STRIDE 1024
#define P1_STRIDE 1024

typedef __attribute__((ext_vector_type(8))) short short8;
typedef __attribute__((ext_vector_type(4))) float f32x4;

__device__ __forceinline__ unsigned short f2bf_rne(float f) {
  union { float f; unsigned u; } v; v.f = f;
  unsigned u = v.u;
  unsigned r = (u + 0x7fffu + ((u >> 16) & 1u)) >> 16;
  return (unsigned short)r;
}
__device__ __forceinline__ float bf2f(unsigned short h) {
  union { unsigned u; float f; } v; v.u = ((unsigned)h) << 16;
  return v.f;
}

// ---------------- mask dtype detection ----------------
__global__ void detect_mask_kernel(const unsigned* __restrict__ m, int* __restrict__ flags) {
  int i = blockIdx.x * 256 + threadIdx.x;
  if (i < NROWS / 4) {
    unsigned v = m[i];
    if (v > 1u) atomicOr(&flags[0], 1);
    if (v != 0u && v != 1u && v != 0x3F800000u) atomicOr(&flags[1], 1);
  }
}

// ---------------- partial -> mean/inv reduction ----------------
__global__ __launch_bounds__(256) void reduce_stats_kernel(
    const float* __restrict__ p, int stride, int nblk, int nch,
    float* __restrict__ mean_out, float* __restrict__ inv_out)
{
  int c = blockIdx.x, tid = threadIdx.x;
  float s = 0.f, q = 0.f;
  for (int j = tid; j < nblk; j += 256) {
    s += p[(size_t)c*stride + j];
    q += p[(size_t)(nch + c)*stride + j];
  }
#pragma unroll
  for (int off = 32; off > 0; off >>= 1) { s += __shfl_xor(s, off); q += __shfl_xor(q, off); }
  __shared__ float ss[4], sq[4];
  if ((tid & 63) == 0) { ss[tid >> 6] = s; sq[tid >> 6] = q; }
  __syncthreads();
  if (tid == 0) {
    float S = ss[0]+ss[1]+ss[2]+ss[3], Q = sq[0]+sq[1]+sq[2]+sq[3];
    float invN = 1.f / (float)NROWS;
    float mean = S * invN;
    float var  = Q * invN - mean*mean;
    mean_out[c] = mean;
    inv_out[c]  = rsqrtf(var + 1e-9f);
  }
}

// ---------------- k1: h0 = k @ W_eff + qc via MFMA (bf16 hi/lo split) ----------------
// W_eff[d][c] = (W0b - W0c)[d][c] + q[d]*W0d[d][c];  qc = b0 + q@(W0a+W0c)
template<bool STORE>
__global__ __launch_bounds__(256) void k1_mfma(
    const float* __restrict__ query, const float* __restrict__ key,
    const float* __restrict__ W0, const float* __restrict__ b0,
    unsigned short* __restrict__ h0, float* __restrict__ p0)
{
  __shared__ __align__(16) unsigned short sWhi[80*72];  // W_eff^T [c][d], stride 72
  __shared__ __align__(16) unsigned short sWlo[80*72];
  __shared__ float sq[64];
  __shared__ float sqc[80];
  __shared__ float sred[160];
  int b = blockIdx.x, tid = threadIdx.x;

  if (tid < 64) sq[tid] = query[b*64 + tid];
  for (int i = tid; i < 160; i += 256) sred[i] = 0.f;
  __syncthreads();
  // stage W_eff transposed, split hi/lo (d-major loop for coalesced W0 reads)
  for (int idx = tid; idx < 64*80; idx += 256) {
    int d = idx / 80, c = idx - d*80;
    float we = (W0[(64+d)*80 + c] - W0[(128+d)*80 + c]) + sq[d]*W0[(192+d)*80 + c];
    unsigned short hi = f2bf_rne(we);
    float lo = we - bf2f(hi);
    sWhi[c*72 + d] = hi;
    sWlo[c*72 + d] = f2bf_rne(lo);
  }
  if (tid < 80) {
    float s = b0[tid];
    for (int d = 0; d < 64; ++d)
      s += sq[d] * (W0[d*80 + tid] + W0[(128+d)*80 + tid]);
    sqc[tid] = s;
  }
  __syncthreads();

  int wv = tid >> 6, l = tid & 63;
  int lm = l & 15, lg = l >> 4;
  // hoist all B fragments into registers: [n][ks][hi/lo]
  short8 bfr[5][2][2];
#pragma unroll
  for (int n = 0; n < 5; ++n)
#pragma unroll
    for (int ks = 0; ks < 2; ++ks) {
      int off = (n*16 + lm)*72 + ks*32 + lg*8;
      bfr[n][ks][0] = *reinterpret_cast<const short8*>(&sWhi[off]);
      bfr[n][ks][1] = *reinterpret_cast<const short8*>(&sWlo[off]);
    }

  float accS[5] = {0,0,0,0,0}, accQ[5] = {0,0,0,0,0};
  const float* keyb = key + (size_t)b*NT*ND;

  for (int mt = wv; mt < 13; mt += 4) {
    int t0 = mt*16;
    int trow = t0 + lm;
    int tld = trow < NT ? trow : NT-1;      // clamp padded rows (masked later)
    const float* arow = keyb + (size_t)tld*ND;
    short8 ahi[2], alo[2];
#pragma unroll
    for (int ks = 0; ks < 2; ++ks) {
      float4 av0 = *reinterpret_cast<const float4*>(arow + ks*32 + lg*8);
      float4 av1 = *reinterpret_cast<const float4*>(arow + ks*32 + lg*8 + 4);
      float xs[8] = {av0.x, av0.y, av0.z, av0.w, av1.x, av1.y, av1.z, av1.w};
#pragma unroll
      for (int j = 0; j < 8; ++j) {
        unsigned short hb = f2bf_rne(xs[j]);
        ahi[ks][j] = (short)hb;
        alo[ks][j] = (short)f2bf_rne(xs[j] - bf2f(hb));
      }
    }
    f32x4 acc[5];
#pragma unroll
    for (int n = 0; n < 5; ++n) {
      float qcv = sqc[n*16 + lm];
      acc[n][0] = qcv; acc[n][1] = qcv; acc[n][2] = qcv; acc[n][3] = qcv;
    }
#pragma unroll
    for (int n = 0; n < 5; ++n)
#pragma unroll
      for (int ks = 0; ks < 2; ++ks) {
        acc[n] = __builtin_amdgcn_mfma_f32_16x16x32_bf16(ahi[ks], bfr[n][ks][0], acc[n], 0, 0, 0);
        acc[n] = __builtin_amdgcn_mfma_f32_16x16x32_bf16(ahi[ks], bfr[n][ks][1], acc[n], 0, 0, 0);
        acc[n] = __builtin_amdgcn_mfma_f32_16x16x32_bf16(alo[ks], bfr[n][ks][0], acc[n], 0, 0, 0);
      }
    // C/D layout (HW-verified): col = lane&15, row = (lane>>4)*4 + reg
#pragma unroll
    for (int n = 0; n < 5; ++n)
#pragma unroll
      for (int r = 0; r < 4; ++r) {
        int row = t0 + lg*4 + r;
        if (row < NT) {
          float h = acc[n][r];
          if (STORE) h0[((size_t)b*NT + row)*NH0 + n*16 + lm] = f2bf_rne(h);
          accS[n] += h; accQ[n] += h*h;
        }
      }
  }
  // reduce stats: lanes with same (lane&15) hold same channel within an n-group
#pragma unroll
  for (int n = 0; n < 5; ++n) {
    accS[n] += __shfl_xor(accS[n], 16); accS[n] += __shfl_xor(accS[n], 32);
    accQ[n] += __shfl_xor(accQ[n], 16); accQ[n] += __shfl_xor(accQ[n], 32);
  }
  if (lg == 0) {
#pragma unroll
    for (int n = 0; n < 5; ++n) {
      atomicAdd(&sred[n*16 + lm], accS[n]);
      atomicAdd(&sred[80 + n*16 + lm], accQ[n]);
    }
  }
  __syncthreads();
  if (tid < 160) p0[(size_t)tid * P0_STRIDE + b] = sred[tid];
}

// ---------------- k2 (load bf16 h0): h1 = dice0(h0)@W1 + b1, stats1 partials ----------------
__global__ __launch_bounds__(256) void k2_kernel(
    const unsigned short* __restrict__ h0, const float* __restrict__ W1,
    const float* __restrict__ b1, const float* __restrict__ alpha0,
    unsigned short* __restrict__ h1, const float* __restrict__ stats,
    float* __restrict__ p1)
{
  __shared__ float sW1[80*40];
  __shared__ float sb1[40];
  __shared__ float sm0[80], si0[80], sa0[80];
  __shared__ float swp[4*80];
  int tid = threadIdx.x;
  for (int idx = tid; idx < 3200; idx += 256) sW1[idx] = W1[idx];
  if (tid < 40) sb1[tid] = b1[tid];
  if (tid < 80) {
    sm0[tid] = stats[tid]; si0[tid] = stats[80 + tid]; sa0[tid] = alpha0[tid];
  }
  __syncthreads();
  size_t r = (size_t)blockIdx.x * 256 + tid;
  const uint4* xr = (const uint4*)(h0 + r*NH0);
  float acc[40];
#pragma unroll
  for (int c = 0; c < 40; ++c) acc[c] = sb1[c];
#pragma unroll 2
  for (int dq = 0; dq < 10; ++dq) {
    uint4 xv = xr[dq];
    unsigned uu[4] = {xv.x, xv.y, xv.z, xv.w};
#pragma unroll
    for (int u = 0; u < 8; ++u) {
      int d = dq*8 + u;
      unsigned short hx = (u & 1) ? (unsigned short)(uu[u>>1] >> 16)
                                  : (unsigned short)(uu[u>>1] & 0xffffu);
      float x = bf2f(hx);
      float xn = (x - sm0[d]) * si0[d];
      float p = 1.f / (1.f + __expf(-xn));
      float y = x * (sa0[d] + p*(1.f - sa0[d]));
      const float4* wr = (const float4*)(sW1 + d*40);
#pragma unroll
      for (int cq = 0; cq < 10; ++cq) {
        float4 w = wr[cq];
        acc[cq*4+0] = fmaf(y, w.x, acc[cq*4+0]);
        acc[cq*4+1] = fmaf(y, w.y, acc[cq*4+1]);
        acc[cq*4+2] = fmaf(y, w.z, acc[cq*4+2]);
        acc[cq*4+3] = fmaf(y, w.w, acc[cq*4+3]);
      }
    }
  }
  uint4* orow = (uint4*)(h1 + r*NH1);
#pragma unroll
  for (int cq = 0; cq < 5; ++cq) {
    uint4 o;
    o.x = (unsigned)f2bf_rne(acc[cq*8+0]) | ((unsigned)f2bf_rne(acc[cq*8+1]) << 16);
    o.y = (unsigned)f2bf_rne(acc[cq*8+2]) | ((unsigned)f2bf_rne(acc[cq*8+3]) << 16);
    o.z = (unsigned)f2bf_rne(acc[cq*8+4]) | ((unsigned)f2bf_rne(acc[cq*8+5]) << 16);
    o.w = (unsigned)f2bf_rne(acc[cq*8+6]) | ((unsigned)f2bf_rne(acc[cq*8+7]) << 16);
    orow[cq] = o;
  }
  int lane = tid & 63, wid = tid >> 6;
#pragma unroll
  for (int c = 0; c < 40; ++c) {
    float s = acc[c], q = acc[c]*acc[c];
#pragma unroll
    for (int off = 32; off > 0; off >>= 1) { s += __shfl_xor(s, off); q += __shfl_xor(q, off); }
    if (lane == 0) { swp[wid*80 + c] = s; swp[wid*80 + 40 + c] = q; }
  }
  __syncthreads();
  if (tid < 80) {
    float v = swp[tid] + swp[80+tid] + swp[160+tid] + swp[240+tid];
    p1[(size_t)tid * P1_STRIDE + blockIdx.x] = v;
  }
}

// ---------------- k2 fallback (recompute h0 in fp32) ----------------
template<bool STOREH1>
__global__ __launch_bounds__(256) void k2_rec_kernel(
    const float* __restrict__ query, const float* __restrict__ key,
    const float* __restrict__ W0, const float* __restrict__ b0,
    const float* __restrict__ W1, const float* __restrict__ b1,
    const float* __restrict__ alpha0,
    unsigned short* __restrict__ h1, const float* __restrict__ stats,
    float* __restrict__ p1)
{
  __shared__ float sWb[64*80], sWd[64*80], sW1[80*40];
  __shared__ float sq[64], sqc[80], sb1[40];
  __shared__ float sm0[80], si0[80], sa0[80];
  __shared__ float swp[4*80];
  int b = blockIdx.x, tid = threadIdx.x;
  for (int idx = tid; idx < 64*80; idx += 256) {
    int d = idx / 80, c = idx - d*80;
    sWb[idx] = W0[(64+d)*80 + c] - W0[(128+d)*80 + c];
    sWd[idx] = W0[(192+d)*80 + c];
  }
  for (int idx = tid; idx < 3200; idx += 256) sW1[idx] = W1[idx];
  if (tid < 64) sq[tid] = query[b*64 + tid];
  if (tid < 40) sb1[tid] = b1[tid];
  if (tid >= 64 && tid < 144) {
    int c = tid - 64;
    sm0[c] = stats[c]; si0[c] = stats[80 + c]; sa0[c] = alpha0[c];
  }
  __syncthreads();
  if (tid < 80) {
    float s = b0[tid];
    for (int d = 0; d < 64; ++d)
      s += sq[d] * (W0[d*80 + tid] + W0[(128+d)*80 + tid]);
    sqc[tid] = s;
  }
  __syncthreads();
  int t = tid;
  bool active = t < NT;
  float h0r[80];
#pragma unroll
  for (int c = 0; c < 80; ++c) h0r[c] = sqc[c];
  const float* krow = key + ((size_t)b*NT + (active ? t : 0))*ND;
  for (int dq = 0; dq < 16; ++dq) {
    float4 kv = ((const float4*)krow)[dq];
#pragma unroll
    for (int u = 0; u < 4; ++u) {
      int d = dq*4 + u;
      float kd = (&kv.x)[u];
      float qk = sq[d] * kd;
#pragma unroll
      for (int c = 0; c < 80; ++c)
        h0r[c] = fmaf(kd, sWb[d*80 + c], fmaf(qk, sWd[d*80 + c], h0r[c]));
    }
  }
  float h1r[40];
#pragma unroll
  for (int c = 0; c < 40; ++c) h1r[c] = sb1[c];
#pragma unroll
  for (int d = 0; d < 80; ++d) {
    float x = h0r[d];
    float xn = (x - sm0[d]) * si0[d];
    float p = 1.f / (1.f + __expf(-xn));
    float y = x * (sa0[d] + p*(1.f - sa0[d]));
#pragma unroll
    for (int c = 0; c < 40; ++c) h1r[c] = fmaf(y, sW1[d*40 + c], h1r[c]);
  }
  if (STOREH1 && active) {
    uint4* orow = (uint4*)(h1 + ((size_t)b*NT + t)*NH1);
#pragma unroll
    for (int cq = 0; cq < 5; ++cq) {
      uint4 o;
      o.x = (unsigned)f2bf_rne(h1r[cq*8+0]) | ((unsigned)f2bf_rne(h1r[cq*8+1]) << 16);
      o.y = (unsigned)f2bf_rne(h1r[cq*8+2]) | ((unsigned)f2bf_rne(h1r[cq*8+3]) << 16);
      o.z = (unsigned)f2bf_rne(h1r[cq*8+4]) | ((unsigned)f2bf_rne(h1r[cq*8+5]) << 16);
      o.w = (unsigned)f2bf_rne(h1r[cq*8+6]) | ((unsigned)f2bf_rne(h1r[cq*8+7]) << 16);
      orow[cq] = o;
    }
  }
  int lane = tid & 63, wid = tid >> 6;
#pragma unroll
  for (int c = 0; c < 40; ++c) {
    float v = active ? h1r[c] : 0.f;
    float s = v, q = v*v;
#pragma unroll
    for (int off = 32; off > 0; off >>= 1) { s += __shfl_xor(s, off); q += __shfl_xor(q, off); }
    if (lane == 0) { swp[wid*80 + c] = s; swp[wid*80 + 40 + c] = q; }
  }
  __syncthreads();
  if (tid < 80) {
    float v = swp[tid] + swp[80+tid] + swp[160+tid] + swp[240+tid];
    p1[(size_t)tid * P1_STRIDE + b] = v;
  }
}

// ---------------- k3: dice1, scores, softmax, attn@key ----------------
__device__ __forceinline__ void softmax_and_out(
    int b, int tid, float sc, float* sp, float* sredm, float* ssum, float* sout,
    const float* __restrict__ key, float* __restrict__ out)
{
  float m = sc;
#pragma unroll
  for (int off = 32; off > 0; off >>= 1) m = fmaxf(m, __shfl_xor(m, off));
  if ((tid & 63) == 0) sredm[tid >> 6] = m;
  __syncthreads();
  float mm = fmaxf(fmaxf(sredm[0], sredm[1]), fmaxf(sredm[2], sredm[3]));
  float e = (sc > -FLT_MAX) ? __expf(sc - mm) : 0.f;
  float sv = e;
#pragma unroll
  for (int off = 32; off > 0; off >>= 1) sv += __shfl_xor(sv, off);
  if ((tid & 63) == 0) ssum[tid >> 6] = sv;
  __syncthreads();
  float inv = 1.f / (ssum[0] + ssum[1] + ssum[2] + ssum[3]);
  sp[tid] = e * inv;
  __syncthreads();
  int wid = tid >> 6, lane = tid & 63;
  const float* keyb = key + (size_t)b*NT*ND;
  float acc = 0.f;
  for (int t = wid; t < NT; t += 4) acc = fmaf(sp[t], keyb[t*ND + lane], acc);
  sout[tid] = acc;
  __syncthreads();
  if (tid < 64) out[b*64 + tid] = sout[tid] + sout[64+tid] + sout[128+tid] + sout[192+tid];
}

__device__ __forceinline__ bool read_mask(const void* mask, int mode, size_t mi) {
  if (mode == 0) return ((const int*)mask)[mi] != 0;
  if (mode == 1) return ((const unsigned char*)mask)[mi] != 0;
  return ((const float*)mask)[mi] != 0.f;
}

__global__ __launch_bounds__(256) void k3_kernel(
    const unsigned short* __restrict__ h1, const float* __restrict__ Wout,
    const float* __restrict__ bout, const float* __restrict__ alpha1,
    const void* __restrict__ mask, const float* __restrict__ key,
    const float* __restrict__ stats, const int* __restrict__ flags,
    float* __restrict__ out)
{
  __shared__ float sWo[40], sm1[40], si1[40], sa1[40];
  __shared__ float sp[256], sredm[4], ssum[4], sout[256];
  int b = blockIdx.x, tid = threadIdx.x;
  if (tid < 40) {
    sWo[tid] = Wout[tid];
    sm1[tid] = stats[160 + tid]; si1[tid] = stats[200 + tid]; sa1[tid] = alpha1[tid];
  }
  __syncthreads();
  int mode = (flags[0] == 0) ? 0 : ((flags[1] == 0) ? 2 : 1);
  float sc = -FLT_MAX;
  if (tid < NT) {
    const uint4* xr = (const uint4*)(h1 + ((size_t)b*NT + tid)*NH1);
    float s = bout[0];
#pragma unroll
    for (int cq = 0; cq < 5; ++cq) {
      uint4 xv = xr[cq];
      unsigned uu[4] = {xv.x, xv.y, xv.z, xv.w};
#pragma unroll
      for (int u = 0; u < 8; ++u) {
        int c = cq*8 + u;
        unsigned short hx = (u & 1) ? (unsigned short)(uu[u>>1] >> 16)
                                    : (unsigned short)(uu[u>>1] & 0xffffu);
        float x = bf2f(hx);
        float xn = (x - sm1[c]) * si1[c];
        float p = 1.f / (1.f + __expf(-xn));
        float y = x * (sa1[c] + p*(1.f - sa1[c]));
        s = fmaf(y, sWo[c], s);
      }
    }
    if (read_mask(mask, mode, (size_t)b*NT + tid)) sc = s;
  }
  softmax_and_out(b, tid, sc, sp, sredm, ssum, sout, key, out);
}

// ---------------- k3 fallback (full recompute) ----------------
__global__ __launch_bounds__(256) void k3_rec_kernel(
    const float* __restrict__ query, const float* __restrict__ key,
    const float* __restrict__ W0, const float* __restrict__ b0,
    const float* __restrict__ W1, const float* __restrict__ b1,
    const float* __restrict__ alpha0, const float* __restrict__ Wout,
    const float* __restrict__ bout, const float* __restrict__ alpha1,
    const void* __restrict__ mask,
    const float* __restrict__ stats, const int* __restrict__ flags,
    float* __restrict__ out)
{
  __shared__ float sWb[64*80], sWd[64*80], sW1[80*40];
  __shared__ float sq[64], sqc[80], sb1[40];
  __shared__ float sm0[80], si0[80], sa0[80];
  __shared__ float sWo[40], sm1[40], si1[40], sa1[40];
  __shared__ float sp[256], sredm[4], ssum[4], sout[256];
  int b = blockIdx.x, tid = threadIdx.x;
  for (int idx = tid; idx < 64*80; idx += 256) {
    int d = idx / 80, c = idx - d*80;
    sWb[idx] = W0[(64+d)*80 + c] - W0[(128+d)*80 + c];
    sWd[idx] = W0[(192+d)*80 + c];
  }
  for (int idx = tid; idx < 3200; idx += 256) sW1[idx] = W1[idx];
  if (tid < 64) sq[tid] = query[b*64 + tid];
  if (tid < 40) sb1[tid] = b1[tid];
  if (tid >= 64 && tid < 144) {
    int c = tid - 64;
    sm0[c] = stats[c]; si0[c] = stats[80 + c]; sa0[c] = alpha0[c];
  }
  if (tid >= 144 && tid < 184) {
    int c = tid - 144;
    sm1[c] = stats[160 + c]; si1[c] = stats[200 + c]; sa1[c] = alpha1[c];
    sWo[c] = Wout[c];
  }
  __syncthreads();
  if (tid < 80) {
    float s = b0[tid];
    for (int d = 0; d < 64; ++d)
      s += sq[d] * (W0[d*80 + tid] + W0[(128+d)*80 + tid]);
    sqc[tid] = s;
  }
  __syncthreads();
  int t = tid;
  bool active = t < NT;
  int mode = (flags[0] == 0) ? 0 : ((flags[1] == 0) ? 2 : 1);
  float sc = -FLT_MAX;
  {
    float h0r[80];
#pragma unroll
    for (int c = 0; c < 80; ++c) h0r[c] = sqc[c];
    const float* krow = key + ((size_t)b*NT + (active ? t : 0))*ND;
    for (int dq = 0; dq < 16; ++dq) {
      float4 kv = ((const float4*)krow)[dq];
#pragma unroll
      for (int u = 0; u < 4; ++u) {
        int d = dq*4 + u;
        float kd = (&kv.x)[u];
        float qk = sq[d] * kd;
#pragma unroll
        for (int c = 0; c < 80; ++c)
          h0r[c] = fmaf(kd, sWb[d*80 + c], fmaf(qk, sWd[d*80 + c], h0r[c]));
      }
    }
    float h1r[40];
#pragma unroll
    for (int c = 0; c < 40; ++c) h1r[c] = sb1[c];
#pragma unroll
    for (int d = 0; d < 80; ++d) {
      float x = h0r[d];
      float xn = (x - sm0[d]) * si0[d];
      float p = 1.f / (1.f + __expf(-xn));
      float y = x * (sa0[d] + p*(1.f - sa0[d]));
#pragma unroll
      for (int c = 0; c < 40; ++c) h1r[c] = fmaf(y, sW1[d*40 + c], h1r[c]);
    }
    float s = bout[0];
#pragma unroll
    for (int c = 0; c < 40; ++c) {
      float x = h1r[c];
      float xn = (x - sm1[c]) * si1[c];
      float p = 1.f / (1.f + __expf(-xn));
      float y = x * (sa1[c] + p*(1.f - sa1[c]));
      s = fmaf(y, sWo[c], s);
    }
    if (active && read_mask(mask, mode, (size_t)b*NT + t)) sc = s;
  }
  softmax_and_out(b, tid, sc, sp, sredm, ssum, sout, key, out);
}

extern "C" void kernel_launch(void* const* d_in, const int* in_sizes, int n_in,
                              void* d_out, int out_size, void* d_ws, size_t ws_size,
                              hipStream_t stream) {
  const float* query  = (const float*)d_in[0];
  const float* key    = (const float*)d_in[1];
  const void*  mask   = d_in[2];
  const float* W0     = (const float*)d_in[3];
  const float* b0     = (const float*)d_in[4];
  const float* alpha0 = (const float*)d_in[5];
  const float* W1     = (const float*)d_in[6];
  const float* b1     = (const float*)d_in[7];
  const float* alpha1 = (const float*)d_in[8];
  const float* Wout   = (const float*)d_in[9];
  const float* bout   = (const float*)d_in[10];
  float* out = (float*)d_out;

  char* wsb = (char*)d_ws;
  float* stats = (float*)wsb;
  int* flags = (int*)(wsb + 240*4);
  const size_t off_p0 = 1024;
  const size_t p0B = (size_t)160 * P0_STRIDE * 4;
  const size_t off_p1 = off_p0 + p0B;
  const size_t p1B = (size_t)80 * P1_STRIDE * 4;
  const size_t off_h0 = off_p1 + p1B;                 // 16B aligned
  const size_t h0B = (size_t)NROWS * NH0 * 2;         // bf16
  const size_t h1B = (size_t)NROWS * NH1 * 2;         // bf16
  unsigned short* h0 = (unsigned short*)(wsb + off_h0);
  bool storeH0 = ws_size >= off_h0 + h0B + h1B;
  bool storeH1 = storeH0 || (ws_size >= off_h0 + h1B);
  unsigned short* h1 = storeH0 ? (unsigned short*)(wsb + off_h0 + h0B)
                               : (unsigned short*)(wsb + off_h0);
  float* p0 = (float*)(wsb + off_p0);
  float* p1 = (float*)(wsb + off_p1);

  hipMemsetAsync(d_ws, 0, 1024, stream);
  detect_mask_kernel<<<200, 256, 0, stream>>>((const unsigned*)mask, flags);

  if (storeH0) {
    k1_mfma<true><<<NB, 256, 0, stream>>>(query, key, W0, b0, h0, p0);
    reduce_stats_kernel<<<80, 256, 0, stream>>>(p0, P0_STRIDE, NB, 80, stats, stats + 80);
    k2_kernel<<<NROWS/256, 256, 0, stream>>>(h0, W1, b1, alpha0, h1, stats, p1);
    reduce_stats_kernel<<<40, 256, 0, stream>>>(p1, P1_STRIDE, NROWS/256, 40, stats + 160, stats + 200);
    k3_kernel<<<NB, 256, 0, stream>>>(h1, Wout, bout, alpha1, mask, key, stats, flags, out);
  } else if (storeH1) {
    k1_mfma<false><<<NB, 256, 0, stream>>>(query, key, W0, b0, nullptr, p0);
    reduce_stats_kernel<<<80, 256, 0, stream>>>(p0, P0_STRIDE, NB, 80, stats, stats + 80);
    k2_rec_kernel<true><<<NB, 256, 0, stream>>>(query, key, W0, b0, W1, b1, alpha0, h1, stats, p1);
    reduce_stats_kernel<<<40, 256, 0, stream>>>(p1, P1_STRIDE, NB, 40, stats + 160, stats + 200);
    k3_kernel<<<NB, 256, 0, stream>>>(h1, Wout, bout, alpha1, mask, key, stats, flags, out);
  } else {
    k1_mfma<false><<<NB, 256, 0, stream>>>(query, key, W0, b0, nullptr, p0);
    reduce_stats_kernel<<<80, 256, 0, stream>>>(p0, P0_STRIDE, NB, 80, stats, stats + 80);
    k2_rec_kernel<false><<<NB, 256, 0, stream>>>(query, key, W0, b0, W1, b1, alpha0, nullptr, stats, p1);
    reduce_stats_kernel<<<40, 256, 0, stream>>>(p1, P1_STRIDE, NB, 40, stats + 160, stats + 200);
    k3_rec_kernel<<<NB, 256, 0, stream>>>(query, key, W0, b0, W1, b1, alpha0, Wout, bout, alpha1,
                                          mask, stats, flags, out);
  }
}

// Round 4
// 120.801 us; speedup vs baseline: 10.2787x; 1.2778x over previous
//
#include <hip/hip_runtime.h>
#include <float.h>

#define NB 1024
#define NT 200
#define ND 64
#define NH0 80
#define NH1 40
#define NROWS (NB*NT)
#define P0_STRIDE 1024
#define P1_STRIDE 1024

typedef __attribute__((ext_vector_type(8))) short short8;
typedef __attribute__((ext_vector_type(4))) float f32x4;

__device__ __forceinline__ unsigned short f2bf_rne(float f) {
  union { float f; unsigned u; } v; v.f = f;
  unsigned u = v.u;
  unsigned r = (u + 0x7fffu + ((u >> 16) & 1u)) >> 16;
  return (unsigned short)r;
}
__device__ __forceinline__ float bf2f(unsigned short h) {
  union { unsigned u; float f; } v; v.u = ((unsigned)h) << 16;
  return v.f;
}

// ---------------- mask dtype detection ----------------
__global__ void detect_mask_kernel(const unsigned* __restrict__ m, int* __restrict__ flags) {
  int i = blockIdx.x * 256 + threadIdx.x;
  if (i < NROWS / 4) {
    unsigned v = m[i];
    if (v > 1u) atomicOr(&flags[0], 1);
    if (v != 0u && v != 1u && v != 0x3F800000u) atomicOr(&flags[1], 1);
  }
}

// ---------------- partial -> mean/inv reduction ----------------
__global__ __launch_bounds__(256) void reduce_stats_kernel(
    const float* __restrict__ p, int stride, int nblk, int nch,
    float* __restrict__ mean_out, float* __restrict__ inv_out)
{
  int c = blockIdx.x, tid = threadIdx.x;
  float s = 0.f, q = 0.f;
  for (int j = tid; j < nblk; j += 256) {
    s += p[(size_t)c*stride + j];
    q += p[(size_t)(nch + c)*stride + j];
  }
#pragma unroll
  for (int off = 32; off > 0; off >>= 1) { s += __shfl_xor(s, off); q += __shfl_xor(q, off); }
  __shared__ float ss[4], sq[4];
  if ((tid & 63) == 0) { ss[tid >> 6] = s; sq[tid >> 6] = q; }
  __syncthreads();
  if (tid == 0) {
    float S = ss[0]+ss[1]+ss[2]+ss[3], Q = sq[0]+sq[1]+sq[2]+sq[3];
    float invN = 1.f / (float)NROWS;
    float mean = S * invN;
    float var  = Q * invN - mean*mean;
    mean_out[c] = mean;
    inv_out[c]  = rsqrtf(var + 1e-9f);
  }
}

// ---------------- k1: h0 = k @ W_eff + qc via MFMA (bf16 hi/lo split) ----------------
template<bool STORE>
__global__ __launch_bounds__(256) void k1_mfma(
    const float* __restrict__ query, const float* __restrict__ key,
    const float* __restrict__ W0, const float* __restrict__ b0,
    unsigned short* __restrict__ h0, float* __restrict__ p0)
{
  __shared__ __align__(16) unsigned short sWhi[80*72];  // W_eff^T [c][d], stride 72
  __shared__ __align__(16) unsigned short sWlo[80*72];
  __shared__ float sq[64];
  __shared__ float sqc[80];
  __shared__ float sred[160];
  int b = blockIdx.x, tid = threadIdx.x;

  if (tid < 64) sq[tid] = query[b*64 + tid];
  for (int i = tid; i < 160; i += 256) sred[i] = 0.f;
  __syncthreads();
  for (int idx = tid; idx < 64*80; idx += 256) {
    int d = idx / 80, c = idx - d*80;
    float we = (W0[(64+d)*80 + c] - W0[(128+d)*80 + c]) + sq[d]*W0[(192+d)*80 + c];
    unsigned short hi = f2bf_rne(we);
    float lo = we - bf2f(hi);
    sWhi[c*72 + d] = hi;
    sWlo[c*72 + d] = f2bf_rne(lo);
  }
  if (tid < 80) {
    float s = b0[tid];
    for (int d = 0; d < 64; ++d)
      s += sq[d] * (W0[d*80 + tid] + W0[(128+d)*80 + tid]);
    sqc[tid] = s;
  }
  __syncthreads();

  int wv = tid >> 6, l = tid & 63;
  int lm = l & 15, lg = l >> 4;
  short8 bfr[5][2][2];
#pragma unroll
  for (int n = 0; n < 5; ++n)
#pragma unroll
    for (int ks = 0; ks < 2; ++ks) {
      int off = (n*16 + lm)*72 + ks*32 + lg*8;
      bfr[n][ks][0] = *reinterpret_cast<const short8*>(&sWhi[off]);
      bfr[n][ks][1] = *reinterpret_cast<const short8*>(&sWlo[off]);
    }

  float accS[5] = {0,0,0,0,0}, accQ[5] = {0,0,0,0,0};
  const float* keyb = key + (size_t)b*NT*ND;

  for (int mt = wv; mt < 13; mt += 4) {
    int t0 = mt*16;
    int trow = t0 + lm;
    int tld = trow < NT ? trow : NT-1;
    const float* arow = keyb + (size_t)tld*ND;
    short8 ahi[2], alo[2];
#pragma unroll
    for (int ks = 0; ks < 2; ++ks) {
      float4 av0 = *reinterpret_cast<const float4*>(arow + ks*32 + lg*8);
      float4 av1 = *reinterpret_cast<const float4*>(arow + ks*32 + lg*8 + 4);
      float xs[8] = {av0.x, av0.y, av0.z, av0.w, av1.x, av1.y, av1.z, av1.w};
#pragma unroll
      for (int j = 0; j < 8; ++j) {
        unsigned short hb = f2bf_rne(xs[j]);
        ahi[ks][j] = (short)hb;
        alo[ks][j] = (short)f2bf_rne(xs[j] - bf2f(hb));
      }
    }
    f32x4 acc[5];
#pragma unroll
    for (int n = 0; n < 5; ++n) {
      float qcv = sqc[n*16 + lm];
      acc[n][0] = qcv; acc[n][1] = qcv; acc[n][2] = qcv; acc[n][3] = qcv;
    }
#pragma unroll
    for (int n = 0; n < 5; ++n)
#pragma unroll
      for (int ks = 0; ks < 2; ++ks) {
        acc[n] = __builtin_amdgcn_mfma_f32_16x16x32_bf16(ahi[ks], bfr[n][ks][0], acc[n], 0, 0, 0);
        acc[n] = __builtin_amdgcn_mfma_f32_16x16x32_bf16(ahi[ks], bfr[n][ks][1], acc[n], 0, 0, 0);
        acc[n] = __builtin_amdgcn_mfma_f32_16x16x32_bf16(alo[ks], bfr[n][ks][0], acc[n], 0, 0, 0);
      }
#pragma unroll
    for (int n = 0; n < 5; ++n)
#pragma unroll
      for (int r = 0; r < 4; ++r) {
        int row = t0 + lg*4 + r;
        if (row < NT) {
          float h = acc[n][r];
          if (STORE) h0[((size_t)b*NT + row)*NH0 + n*16 + lm] = f2bf_rne(h);
          accS[n] += h; accQ[n] += h*h;
        }
      }
  }
#pragma unroll
  for (int n = 0; n < 5; ++n) {
    accS[n] += __shfl_xor(accS[n], 16); accS[n] += __shfl_xor(accS[n], 32);
    accQ[n] += __shfl_xor(accQ[n], 16); accQ[n] += __shfl_xor(accQ[n], 32);
  }
  if (lg == 0) {
#pragma unroll
    for (int n = 0; n < 5; ++n) {
      atomicAdd(&sred[n*16 + lm], accS[n]);
      atomicAdd(&sred[80 + n*16 + lm], accQ[n]);
    }
  }
  __syncthreads();
  if (tid < 160) p0[(size_t)tid * P0_STRIDE + b] = sred[tid];
}

// ---------------- k2: h1 = dice0(h0)@W1 + b1 via MFMA ----------------
__global__ __launch_bounds__(256) void k2_mfma(
    const unsigned short* __restrict__ h0, const float* __restrict__ W1,
    const float* __restrict__ b1, const float* __restrict__ alpha0,
    unsigned short* __restrict__ h1, const float* __restrict__ stats,
    float* __restrict__ p1)
{
  __shared__ __align__(16) unsigned short sWhi[48*96];  // W1^T [c][k], c pad 48, k pad 96
  __shared__ __align__(16) unsigned short sWlo[48*96];
  __shared__ float sm0[96], si0[96], sa0[96];
  __shared__ float sb1[48];
  __shared__ float sred[80];
  int tid = threadIdx.x;
  for (int idx = tid; idx < 48*96; idx += 256) {
    int c = idx / 96, k = idx - c*96;
    float w = (c < 40 && k < 80) ? W1[k*40 + c] : 0.f;
    unsigned short hi = f2bf_rne(w);
    sWhi[idx] = hi;
    sWlo[idx] = f2bf_rne(w - bf2f(hi));
  }
  if (tid < 96) {
    sm0[tid] = (tid < 80) ? stats[tid] : 0.f;
    si0[tid] = (tid < 80) ? stats[80 + tid] : 0.f;
    sa0[tid] = (tid < 80) ? alpha0[tid] : 0.f;
  }
  if (tid >= 96 && tid < 144) sb1[tid-96] = (tid-96 < 40) ? b1[tid-96] : 0.f;
  if (tid >= 144 && tid < 224) sred[tid-144] = 0.f;
  __syncthreads();

  int wv = tid >> 6, l = tid & 63, lm = l & 15, lg = l >> 4;

  short8 bfr[3][3][2];
#pragma unroll
  for (int n = 0; n < 3; ++n)
#pragma unroll
    for (int ks = 0; ks < 3; ++ks) {
      int off = (n*16 + lm)*96 + ks*32 + lg*8;
      bfr[n][ks][0] = *reinterpret_cast<const short8*>(&sWhi[off]);
      bfr[n][ks][1] = *reinterpret_cast<const short8*>(&sWlo[off]);
    }
  // dice params for this lane's fixed k positions
  float dm[3][8], di[3][8], da[3][8];
#pragma unroll
  for (int ks = 0; ks < 3; ++ks) {
    int k0 = ks*32 + lg*8;
#pragma unroll
    for (int j = 0; j < 8; ++j) {
      dm[ks][j] = sm0[k0+j]; di[ks][j] = si0[k0+j]; da[ks][j] = sa0[k0+j];
    }
  }

  float accS[3] = {0,0,0}, accQ[3] = {0,0,0};
  size_t row0 = (size_t)blockIdx.x*256 + wv*64;

  for (int mt = 0; mt < 4; ++mt) {
    size_t row = row0 + mt*16 + lm;
    const unsigned short* arow = h0 + row*NH0;
    short8 ya[3];
#pragma unroll
    for (int ks = 0; ks < 3; ++ks) {
      int el0 = ks*32 + lg*8;
      int elc = (el0 < 80) ? el0 : 0;   // clamp; garbage k>=80 killed by zero-padded B
      uint4 xv = *reinterpret_cast<const uint4*>(arow + elc);
      unsigned uu[4] = {xv.x, xv.y, xv.z, xv.w};
#pragma unroll
      for (int j = 0; j < 8; ++j) {
        unsigned short hx = (j & 1) ? (unsigned short)(uu[j>>1] >> 16)
                                    : (unsigned short)(uu[j>>1] & 0xffffu);
        float x = bf2f(hx);
        float xn = (x - dm[ks][j]) * di[ks][j];
        float pp = 1.f / (1.f + __expf(-xn));
        float y = x * (da[ks][j] + pp*(1.f - da[ks][j]));
        ya[ks][j] = (short)f2bf_rne(y);
      }
    }
    f32x4 acc[3];
#pragma unroll
    for (int n = 0; n < 3; ++n) {
      float bv = sb1[n*16 + lm];
      acc[n][0] = bv; acc[n][1] = bv; acc[n][2] = bv; acc[n][3] = bv;
    }
#pragma unroll
    for (int n = 0; n < 3; ++n)
#pragma unroll
      for (int ks = 0; ks < 3; ++ks) {
        acc[n] = __builtin_amdgcn_mfma_f32_16x16x32_bf16(ya[ks], bfr[n][ks][0], acc[n], 0, 0, 0);
        acc[n] = __builtin_amdgcn_mfma_f32_16x16x32_bf16(ya[ks], bfr[n][ks][1], acc[n], 0, 0, 0);
      }
    // C layout: row = lg*4+r, col = n*16+lm
#pragma unroll
    for (int n = 0; n < 3; ++n) {
      int c = n*16 + lm;
#pragma unroll
      for (int r = 0; r < 4; ++r) {
        float h = acc[n][r];
        if (c < 40) {
          size_t orow = row0 + mt*16 + lg*4 + r;
          h1[orow*NH1 + c] = f2bf_rne(h);
          accS[n] += h; accQ[n] += h*h;
        }
      }
    }
  }
#pragma unroll
  for (int n = 0; n < 3; ++n) {
    accS[n] += __shfl_xor(accS[n], 16); accS[n] += __shfl_xor(accS[n], 32);
    accQ[n] += __shfl_xor(accQ[n], 16); accQ[n] += __shfl_xor(accQ[n], 32);
  }
  if (lg == 0) {
#pragma unroll
    for (int n = 0; n < 3; ++n) {
      int c = n*16 + lm;
      if (c < 40) { atomicAdd(&sred[c], accS[n]); atomicAdd(&sred[40 + c], accQ[n]); }
    }
  }
  __syncthreads();
  if (tid < 80) p1[(size_t)tid * P1_STRIDE + blockIdx.x] = sred[tid];
}

// ---------------- k2 fallback (recompute h0 in fp32) ----------------
template<bool STOREH1>
__global__ __launch_bounds__(256) void k2_rec_kernel(
    const float* __restrict__ query, const float* __restrict__ key,
    const float* __restrict__ W0, const float* __restrict__ b0,
    const float* __restrict__ W1, const float* __restrict__ b1,
    const float* __restrict__ alpha0,
    unsigned short* __restrict__ h1, const float* __restrict__ stats,
    float* __restrict__ p1)
{
  __shared__ float sWb[64*80], sWd[64*80], sW1[80*40];
  __shared__ float sq[64], sqc[80], sb1[40];
  __shared__ float sm0[80], si0[80], sa0[80];
  __shared__ float swp[4*80];
  int b = blockIdx.x, tid = threadIdx.x;
  for (int idx = tid; idx < 64*80; idx += 256) {
    int d = idx / 80, c = idx - d*80;
    sWb[idx] = W0[(64+d)*80 + c] - W0[(128+d)*80 + c];
    sWd[idx] = W0[(192+d)*80 + c];
  }
  for (int idx = tid; idx < 3200; idx += 256) sW1[idx] = W1[idx];
  if (tid < 64) sq[tid] = query[b*64 + tid];
  if (tid < 40) sb1[tid] = b1[tid];
  if (tid >= 64 && tid < 144) {
    int c = tid - 64;
    sm0[c] = stats[c]; si0[c] = stats[80 + c]; sa0[c] = alpha0[c];
  }
  __syncthreads();
  if (tid < 80) {
    float s = b0[tid];
    for (int d = 0; d < 64; ++d)
      s += sq[d] * (W0[d*80 + tid] + W0[(128+d)*80 + tid]);
    sqc[tid] = s;
  }
  __syncthreads();
  int t = tid;
  bool active = t < NT;
  float h0r[80];
#pragma unroll
  for (int c = 0; c < 80; ++c) h0r[c] = sqc[c];
  const float* krow = key + ((size_t)b*NT + (active ? t : 0))*ND;
  for (int dq = 0; dq < 16; ++dq) {
    float4 kv = ((const float4*)krow)[dq];
#pragma unroll
    for (int u = 0; u < 4; ++u) {
      int d = dq*4 + u;
      float kd = (&kv.x)[u];
      float qk = sq[d] * kd;
#pragma unroll
      for (int c = 0; c < 80; ++c)
        h0r[c] = fmaf(kd, sWb[d*80 + c], fmaf(qk, sWd[d*80 + c], h0r[c]));
    }
  }
  float h1r[40];
#pragma unroll
  for (int c = 0; c < 40; ++c) h1r[c] = sb1[c];
#pragma unroll
  for (int d = 0; d < 80; ++d) {
    float x = h0r[d];
    float xn = (x - sm0[d]) * si0[d];
    float p = 1.f / (1.f + __expf(-xn));
    float y = x * (sa0[d] + p*(1.f - sa0[d]));
#pragma unroll
    for (int c = 0; c < 40; ++c) h1r[c] = fmaf(y, sW1[d*40 + c], h1r[c]);
  }
  if (STOREH1 && active) {
    uint4* orow = (uint4*)(h1 + ((size_t)b*NT + t)*NH1);
#pragma unroll
    for (int cq = 0; cq < 5; ++cq) {
      uint4 o;
      o.x = (unsigned)f2bf_rne(h1r[cq*8+0]) | ((unsigned)f2bf_rne(h1r[cq*8+1]) << 16);
      o.y = (unsigned)f2bf_rne(h1r[cq*8+2]) | ((unsigned)f2bf_rne(h1r[cq*8+3]) << 16);
      o.z = (unsigned)f2bf_rne(h1r[cq*8+4]) | ((unsigned)f2bf_rne(h1r[cq*8+5]) << 16);
      o.w = (unsigned)f2bf_rne(h1r[cq*8+6]) | ((unsigned)f2bf_rne(h1r[cq*8+7]) << 16);
      orow[cq] = o;
    }
  }
  int lane = tid & 63, wid = tid >> 6;
#pragma unroll
  for (int c = 0; c < 40; ++c) {
    float v = active ? h1r[c] : 0.f;
    float s = v, q = v*v;
#pragma unroll
    for (int off = 32; off > 0; off >>= 1) { s += __shfl_xor(s, off); q += __shfl_xor(q, off); }
    if (lane == 0) { swp[wid*80 + c] = s; swp[wid*80 + 40 + c] = q; }
  }
  __syncthreads();
  if (tid < 80) {
    float v = swp[tid] + swp[80+tid] + swp[160+tid] + swp[240+tid];
    p1[(size_t)tid * P1_STRIDE + b] = v;
  }
}

// ---------------- k3: dice1, scores, softmax, attn@key ----------------
__device__ __forceinline__ void softmax_and_out(
    int b, int tid, float sc, float* sp, float* sredm, float* ssum, float* sout,
    const float* __restrict__ key, float* __restrict__ out)
{
  float m = sc;
#pragma unroll
  for (int off = 32; off > 0; off >>= 1) m = fmaxf(m, __shfl_xor(m, off));
  if ((tid & 63) == 0) sredm[tid >> 6] = m;
  __syncthreads();
  float mm = fmaxf(fmaxf(sredm[0], sredm[1]), fmaxf(sredm[2], sredm[3]));
  float e = (sc > -FLT_MAX) ? __expf(sc - mm) : 0.f;
  float sv = e;
#pragma unroll
  for (int off = 32; off > 0; off >>= 1) sv += __shfl_xor(sv, off);
  if ((tid & 63) == 0) ssum[tid >> 6] = sv;
  __syncthreads();
  float inv = 1.f / (ssum[0] + ssum[1] + ssum[2] + ssum[3]);
  sp[tid] = e * inv;
  __syncthreads();
  int wid = tid >> 6, lane = tid & 63;
  const float* keyb = key + (size_t)b*NT*ND;
  float acc = 0.f;
  for (int t = wid; t < NT; t += 4) acc = fmaf(sp[t], keyb[t*ND + lane], acc);
  sout[tid] = acc;
  __syncthreads();
  if (tid < 64) out[b*64 + tid] = sout[tid] + sout[64+tid] + sout[128+tid] + sout[192+tid];
}

__device__ __forceinline__ bool read_mask(const void* mask, int mode, size_t mi) {
  if (mode == 0) return ((const int*)mask)[mi] != 0;
  if (mode == 1) return ((const unsigned char*)mask)[mi] != 0;
  return ((const float*)mask)[mi] != 0.f;
}

__global__ __launch_bounds__(256) void k3_kernel(
    const unsigned short* __restrict__ h1, const float* __restrict__ Wout,
    const float* __restrict__ bout, const float* __restrict__ alpha1,
    const void* __restrict__ mask, const float* __restrict__ key,
    const float* __restrict__ stats, const int* __restrict__ flags,
    float* __restrict__ out)
{
  __shared__ float sWo[40], sm1[40], si1[40], sa1[40];
  __shared__ float sp[256], sredm[4], ssum[4], sout[256];
  int b = blockIdx.x, tid = threadIdx.x;
  if (tid < 40) {
    sWo[tid] = Wout[tid];
    sm1[tid] = stats[160 + tid]; si1[tid] = stats[200 + tid]; sa1[tid] = alpha1[tid];
  }
  __syncthreads();
  int mode = (flags[0] == 0) ? 0 : ((flags[1] == 0) ? 2 : 1);
  float sc = -FLT_MAX;
  if (tid < NT) {
    const uint4* xr = (const uint4*)(h1 + ((size_t)b*NT + tid)*NH1);
    float s = bout[0];
#pragma unroll
    for (int cq = 0; cq < 5; ++cq) {
      uint4 xv = xr[cq];
      unsigned uu[4] = {xv.x, xv.y, xv.z, xv.w};
#pragma unroll
      for (int u = 0; u < 8; ++u) {
        int c = cq*8 + u;
        unsigned short hx = (u & 1) ? (unsigned short)(uu[u>>1] >> 16)
                                    : (unsigned short)(uu[u>>1] & 0xffffu);
        float x = bf2f(hx);
        float xn = (x - sm1[c]) * si1[c];
        float p = 1.f / (1.f + __expf(-xn));
        float y = x * (sa1[c] + p*(1.f - sa1[c]));
        s = fmaf(y, sWo[c], s);
      }
    }
    if (read_mask(mask, mode, (size_t)b*NT + tid)) sc = s;
  }
  softmax_and_out(b, tid, sc, sp, sredm, ssum, sout, key, out);
}

// ---------------- k3 fallback (full recompute) ----------------
__global__ __launch_bounds__(256) void k3_rec_kernel(
    const float* __restrict__ query, const float* __restrict__ key,
    const float* __restrict__ W0, const float* __restrict__ b0,
    const float* __restrict__ W1, const float* __restrict__ b1,
    const float* __restrict__ alpha0, const float* __restrict__ Wout,
    const float* __restrict__ bout, const float* __restrict__ alpha1,
    const void* __restrict__ mask,
    const float* __restrict__ stats, const int* __restrict__ flags,
    float* __restrict__ out)
{
  __shared__ float sWb[64*80], sWd[64*80], sW1[80*40];
  __shared__ float sq[64], sqc[80], sb1[40];
  __shared__ float sm0[80], si0[80], sa0[80];
  __shared__ float sWo[40], sm1[40], si1[40], sa1[40];
  __shared__ float sp[256], sredm[4], ssum[4], sout[256];
  int b = blockIdx.x, tid = threadIdx.x;
  for (int idx = tid; idx < 64*80; idx += 256) {
    int d = idx / 80, c = idx - d*80;
    sWb[idx] = W0[(64+d)*80 + c] - W0[(128+d)*80 + c];
    sWd[idx] = W0[(192+d)*80 + c];
  }
  for (int idx = tid; idx < 3200; idx += 256) sW1[idx] = W1[idx];
  if (tid < 64) sq[tid] = query[b*64 + tid];
  if (tid < 40) sb1[tid] = b1[tid];
  if (tid >= 64 && tid < 144) {
    int c = tid - 64;
    sm0[c] = stats[c]; si0[c] = stats[80 + c]; sa0[c] = alpha0[c];
  }
  if (tid >= 144 && tid < 184) {
    int c = tid - 144;
    sm1[c] = stats[160 + c]; si1[c] = stats[200 + c]; sa1[c] = alpha1[c];
    sWo[c] = Wout[c];
  }
  __syncthreads();
  if (tid < 80) {
    float s = b0[tid];
    for (int d = 0; d < 64; ++d)
      s += sq[d] * (W0[d*80 + tid] + W0[(128+d)*80 + tid]);
    sqc[tid] = s;
  }
  __syncthreads();
  int t = tid;
  bool active = t < NT;
  int mode = (flags[0] == 0) ? 0 : ((flags[1] == 0) ? 2 : 1);
  float sc = -FLT_MAX;
  {
    float h0r[80];
#pragma unroll
    for (int c = 0; c < 80; ++c) h0r[c] = sqc[c];
    const float* krow = key + ((size_t)b*NT + (active ? t : 0))*ND;
    for (int dq = 0; dq < 16; ++dq) {
      float4 kv = ((const float4*)krow)[dq];
#pragma unroll
      for (int u = 0; u < 4; ++u) {
        int d = dq*4 + u;
        float kd = (&kv.x)[u];
        float qk = sq[d] * kd;
#pragma unroll
        for (int c = 0; c < 80; ++c)
          h0r[c] = fmaf(kd, sWb[d*80 + c], fmaf(qk, sWd[d*80 + c], h0r[c]));
      }
    }
    float h1r[40];
#pragma unroll
    for (int c = 0; c < 40; ++c) h1r[c] = sb1[c];
#pragma unroll
    for (int d = 0; d < 80; ++d) {
      float x = h0r[d];
      float xn = (x - sm0[d]) * si0[d];
      float p = 1.f / (1.f + __expf(-xn));
      float y = x * (sa0[d] + p*(1.f - sa0[d]));
#pragma unroll
      for (int c = 0; c < 40; ++c) h1r[c] = fmaf(y, sW1[d*40 + c], h1r[c]);
    }
    float s = bout[0];
#pragma unroll
    for (int c = 0; c < 40; ++c) {
      float x = h1r[c];
      float xn = (x - sm1[c]) * si1[c];
      float p = 1.f / (1.f + __expf(-xn));
      float y = x * (sa1[c] + p*(1.f - sa1[c]));
      s = fmaf(y, sWo[c], s);
    }
    if (active && read_mask(mask, mode, (size_t)b*NT + t)) sc = s;
  }
  softmax_and_out(b, tid, sc, sp, sredm, ssum, sout, key, out);
}

extern "C" void kernel_launch(void* const* d_in, const int* in_sizes, int n_in,
                              void* d_out, int out_size, void* d_ws, size_t ws_size,
                              hipStream_t stream) {
  const float* query  = (const float*)d_in[0];
  const float* key    = (const float*)d_in[1];
  const void*  mask   = d_in[2];
  const float* W0     = (const float*)d_in[3];
  const float* b0     = (const float*)d_in[4];
  const float* alpha0 = (const float*)d_in[5];
  const float* W1     = (const float*)d_in[6];
  const float* b1     = (const float*)d_in[7];
  const float* alpha1 = (const float*)d_in[8];
  const float* Wout   = (const float*)d_in[9];
  const float* bout   = (const float*)d_in[10];
  float* out = (float*)d_out;

  char* wsb = (char*)d_ws;
  float* stats = (float*)wsb;
  int* flags = (int*)(wsb + 240*4);
  const size_t off_p0 = 1024;
  const size_t p0B = (size_t)160 * P0_STRIDE * 4;
  const size_t off_p1 = off_p0 + p0B;
  const size_t p1B = (size_t)80 * P1_STRIDE * 4;
  const size_t off_h0 = off_p1 + p1B;
  const size_t h0B = (size_t)NROWS * NH0 * 2;
  const size_t h1B = (size_t)NROWS * NH1 * 2;
  unsigned short* h0 = (unsigned short*)(wsb + off_h0);
  bool storeH0 = ws_size >= off_h0 + h0B + h1B;
  bool storeH1 = storeH0 || (ws_size >= off_h0 + h1B);
  unsigned short* h1 = storeH0 ? (unsigned short*)(wsb + off_h0 + h0B)
                               : (unsigned short*)(wsb + off_h0);
  float* p0 = (float*)(wsb + off_p0);
  float* p1 = (float*)(wsb + off_p1);

  hipMemsetAsync(d_ws, 0, 1024, stream);
  detect_mask_kernel<<<200, 256, 0, stream>>>((const unsigned*)mask, flags);

  if (storeH0) {
    k1_mfma<true><<<NB, 256, 0, stream>>>(query, key, W0, b0, h0, p0);
    reduce_stats_kernel<<<80, 256, 0, stream>>>(p0, P0_STRIDE, NB, 80, stats, stats + 80);
    k2_mfma<<<NROWS/256, 256, 0, stream>>>(h0, W1, b1, alpha0, h1, stats, p1);
    reduce_stats_kernel<<<40, 256, 0, stream>>>(p1, P1_STRIDE, NROWS/256, 40, stats + 160, stats + 200);
    k3_kernel<<<NB, 256, 0, stream>>>(h1, Wout, bout, alpha1, mask, key, stats, flags, out);
  } else if (storeH1) {
    k1_mfma<false><<<NB, 256, 0, stream>>>(query, key, W0, b0, nullptr, p0);
    reduce_stats_kernel<<<80, 256, 0, stream>>>(p0, P0_STRIDE, NB, 80, stats, stats + 80);
    k2_rec_kernel<true><<<NB, 256, 0, stream>>>(query, key, W0, b0, W1, b1, alpha0, h1, stats, p1);
    reduce_stats_kernel<<<40, 256, 0, stream>>>(p1, P1_STRIDE, NB, 40, stats + 160, stats + 200);
    k3_kernel<<<NB, 256, 0, stream>>>(h1, Wout, bout, alpha1, mask, key, stats, flags, out);
  } else {
    k1_mfma<false><<<NB, 256, 0, stream>>>(query, key, W0, b0, nullptr, p0);
    reduce_stats_kernel<<<80, 256, 0, stream>>>(p0, P0_STRIDE, NB, 80, stats, stats + 80);
    k2_rec_kernel<false><<<NB, 256, 0, stream>>>(query, key, W0, b0, W1, b1, alpha0, nullptr, stats, p1);
    reduce_stats_kernel<<<40, 256, 0, stream>>>(p1, P1_STRIDE, NB, 40, stats + 160, stats + 200);
    k3_rec_kernel<<<NB, 256, 0, stream>>>(query, key, W0, b0, W1, b1, alpha0, Wout, bout, alpha1,
                                          mask, stats, flags, out);
  }
}